// Round 2
// baseline (242.987 us; speedup 1.0000x reference)
//
#include <hip/hip_runtime.h>
#include <math.h>
#include <stdint.h>

// TreeLSTM, 32 complete binary trees depth 10, heap order, d=128.
// R8: post-mortem of R7: __launch_bounds__ min-waves clamp forced 64-reg
//     budget while aW/bU fragments alone are 64 VGPRs -> massive scratch
//     spill (FETCH+8MB WRITE+20MB, dur +10us). Fix: all MFMA kernels at
//     (512,2) [256-reg budget]. gemm_leaf gets latency hiding via software
//     pipeline instead of occupancy: persistent 256-block grid, 4 tiles per
//     block, double-buffered LDS, raw s_barrier + lgkmcnt(0) only (no vmcnt
//     drain), next-tile loads issued before the barrier. tail_k prefetches
//     next group's wx/cglob into regs during current group's epilogue.

#define NTREES 32
#define MTREE 2047
#define NNODES (NTREES * MTREE)   // 65504

typedef __attribute__((ext_vector_type(8))) short bf16x8;
typedef __attribute__((ext_vector_type(4))) float f32x4;

__device__ __forceinline__ float sigmoidf_(float x) {
    return 1.0f / (1.0f + __expf(-x));
}
__device__ __forceinline__ float tanhf_(float x) {
    x = fminf(fmaxf(x, -10.0f), 10.0f);
    float e = __expf(2.0f * x);
    return (e - 1.0f) / (e + 1.0f);
}
__device__ __forceinline__ float bf2f(uint16_t b) {
    union { uint32_t u; float f; } v; v.u = ((uint32_t)b) << 16; return v.f;
}
__device__ __forceinline__ uint16_t f2bf(float f) {
    union { float f; uint32_t u; } v; v.f = f;
    uint32_t r = v.u + 0x7FFF + ((v.u >> 16) & 1);   // RNE
    return (uint16_t)(r >> 16);
}
__device__ __forceinline__ uint4 pack_bf8(float4 a, float4 b) {
    uint4 r;
    r.x = (uint32_t)f2bf(a.x) | ((uint32_t)f2bf(a.y) << 16);
    r.y = (uint32_t)f2bf(a.z) | ((uint32_t)f2bf(a.w) << 16);
    r.z = (uint32_t)f2bf(b.x) | ((uint32_t)f2bf(b.y) << 16);
    r.w = (uint32_t)f2bf(b.z) | ((uint32_t)f2bf(b.w) << 16);
    return r;
}

// Swizzled LDS layout: bf16 rows of 128 (16 chunks of 16B), XOR by row&7.
#define SWZ(row, chunk) ((row) * 128 + (((chunk) ^ ((row) & 7)) * 8))

// ---------------------------------------------------------------------------
__global__ __launch_bounds__(128) void prep_k(const float* __restrict__ Wiou,
                                              const float* __restrict__ Wf,
                                              const float* __restrict__ Uiou,
                                              const float* __restrict__ Uf,
                                              const float* __restrict__ biou,
                                              const float* __restrict__ bf,
                                              uint16_t* __restrict__ WT,
                                              uint16_t* __restrict__ UT,
                                              float* __restrict__ biasS) {
    int n = blockIdx.x, k = threadIdx.x;
    if (n < 512) {
        WT[n * 128 + k] = f2bf(n < 384 ? Wiou[k * 384 + n] : Wf[k * 128 + (n - 384)]);
    } else if (n < 1024) {
        int m = n - 512;
        UT[m * 128 + k] = f2bf(m < 384 ? Uiou[k * 384 + m] : Uf[k * 128 + (m - 384)]);
    } else {
#pragma unroll
        for (int r = 0; r < 4; ++r) {
            int j = r * 128 + k;
            biasS[j] = j < 384 ? biou[j] : bf[j - 384];
        }
    }
}

// ---------------------------------------------------------------------------
// Fused GEMM + leaf epilogue, persistent software pipeline.
// Grid 256 blocks (1/CU), 4 x 64-node tiles each, double-buffered LDS.
// wx layout: wx[v*512 + col*4 + gate], gate = {0:i,1:o,2:u,3:f}.
__global__ __launch_bounds__(512, 2) void gemm_leaf_k(const float* __restrict__ F,
                                                      const uint16_t* __restrict__ WT,
                                                      const float* __restrict__ biasS,
                                                      uint16_t* __restrict__ wx,
                                                      float* __restrict__ h,
                                                      float* __restrict__ c) {
    __shared__ uint16_t Fs[2][64 * 128];   // 2 x 16 KB
    const int tid = threadIdx.x;
    const int w = tid >> 6, lane = tid & 63, q = lane >> 4, l15 = lane & 15;
    const int nbase = blockIdx.x * 256;
    const int srow = tid >> 4;    // 0..31 (staging row within half-tile)
    const int scx = tid & 15;     // staging 16B chunk

    bf16x8 aW[4][4];
    float4 bias4[4];
#pragma unroll
    for (int s = 0; s < 4; ++s) {
        int row = (w + s * 8) * 16 + l15;
#pragma unroll
        for (int kc = 0; kc < 4; ++kc)
            aW[s][kc] = *(const bf16x8*)(WT + (size_t)row * 128 + kc * 32 + q * 8);
        bias4[s] = *(const float4*)(biasS + (w + s * 8) * 16 + q * 4);
    }

    // prologue: issue tile-0 loads into regs
    float4 c0[2], c1[2];
#pragma unroll
    for (int t = 0; t < 2; ++t) {
        int v = nbase + t * 32 + srow; v = v < NNODES ? v : NNODES - 1;
        const float* src = F + (size_t)v * 128 + scx * 8;
        c0[t] = *(const float4*)src;
        c1[t] = *(const float4*)(src + 4);
    }

#pragma unroll
    for (int tt = 0; tt < 4; ++tt) {
        uint16_t* buf = Fs[tt & 1];
        // pack current tile regs -> LDS
#pragma unroll
        for (int t = 0; t < 2; ++t)
            *(uint4*)&buf[SWZ(t * 32 + srow, scx)] = pack_bf8(c0[t], c1[t]);
        // issue next tile's global loads (in flight across barrier + compute)
        if (tt < 3) {
#pragma unroll
            for (int t = 0; t < 2; ++t) {
                int v = nbase + (tt + 1) * 64 + t * 32 + srow; v = v < NNODES ? v : NNODES - 1;
                const float* src = F + (size_t)v * 128 + scx * 8;
                c0[t] = *(const float4*)src;
                c1[t] = *(const float4*)(src + 4);
            }
        }
        // raw barrier: only LDS writes must drain; prefetch loads stay in flight
        asm volatile("s_waitcnt lgkmcnt(0)" ::: "memory");
        __builtin_amdgcn_s_barrier();
        __builtin_amdgcn_sched_barrier(0);

        const int n0 = nbase + tt * 64;
#pragma unroll
        for (int nt = 0; nt < 4; ++nt) {
            bf16x8 b[4];
#pragma unroll
            for (int kc = 0; kc < 4; ++kc)
                b[kc] = *(const bf16x8*)&buf[SWZ(nt * 16 + l15, kc * 4 + q)];
            f32x4 acc[4] = {};
#pragma unroll
            for (int s = 0; s < 4; ++s)
#pragma unroll
                for (int kc = 0; kc < 4; ++kc)
                    acc[s] = __builtin_amdgcn_mfma_f32_16x16x32_bf16(aW[s][kc], b[kc], acc[s], 0, 0, 0);

            int node = n0 + nt * 16 + l15;
            bool nvalid = node < NNODES;
            int v = nvalid ? node : NNODES - 1;
            int tree = v / 2047;
            int j = v - tree * 2047;
            bool leaf = j >= 1023;
            float pi[4], po[4], pu[4], pf[4];
#pragma unroll
            for (int r = 0; r < 4; ++r) {
                pi[r] = acc[0][r] + bias4[0][r];
                po[r] = acc[1][r] + bias4[1][r];
                pu[r] = acc[2][r] + bias4[2][r];
                pf[r] = acc[3][r] + bias4[3][r];
            }
            int colb = w * 16 + q * 4;
            if (nvalid && leaf) {
                float cv[4], hv[4];
#pragma unroll
                for (int r = 0; r < 4; ++r) {
                    float iv = sigmoidf_(pi[r]);
                    float ov = sigmoidf_(po[r]);
                    float uv = tanhf_(pu[r]);
                    float cn = iv * uv;
                    cv[r] = cn;
                    hv[r] = ov * tanhf_(cn);
                }
                *(float4*)&c[(size_t)v * 128 + colb] = *(float4*)cv;
                *(float4*)&h[(size_t)v * 128 + colb] = *(float4*)hv;
            }
            if (nvalid && !leaf) {
                uint4 w0, w1;
                w0.x = (uint32_t)f2bf(pi[0]) | ((uint32_t)f2bf(po[0]) << 16);
                w0.y = (uint32_t)f2bf(pu[0]) | ((uint32_t)f2bf(pf[0]) << 16);
                w0.z = (uint32_t)f2bf(pi[1]) | ((uint32_t)f2bf(po[1]) << 16);
                w0.w = (uint32_t)f2bf(pu[1]) | ((uint32_t)f2bf(pf[1]) << 16);
                w1.x = (uint32_t)f2bf(pi[2]) | ((uint32_t)f2bf(po[2]) << 16);
                w1.y = (uint32_t)f2bf(pu[2]) | ((uint32_t)f2bf(pf[2]) << 16);
                w1.z = (uint32_t)f2bf(pi[3]) | ((uint32_t)f2bf(po[3]) << 16);
                w1.w = (uint32_t)f2bf(pf[3] * 0.0f + pi[3]) | ((uint32_t)f2bf(po[3]) << 16);
                // (re-derive w1.z/w1.w cleanly below to avoid typo risk)
                w1.z = (uint32_t)f2bf(pi[3]) | ((uint32_t)f2bf(po[3]) << 16);
                w1.w = (uint32_t)f2bf(pu[3]) | ((uint32_t)f2bf(pf[3]) << 16);
                uint16_t* wr = wx + (size_t)v * 512 + colb * 4;
                *(uint4*)(wr) = w0;
                *(uint4*)(wr + 8) = w1;
            }
        }
        // no trailing barrier needed: next pack writes the other buffer, and
        // the following barrier (after that pack) orders reuse two tiles out.
    }
}

// ---------------------------------------------------------------------------
__device__ __forceinline__ void load_bU(const uint16_t* __restrict__ UT, bf16x8 bU[4][4]) {
    const int tid = threadIdx.x;
    const int w = tid >> 6, lane = tid & 63, q = lane >> 4, l15 = lane & 15;
#pragma unroll
    for (int s = 0; s < 4; ++s) {
        int row = (w + s * 8) * 16 + l15;   // s: 0=i,1=o,2=u,3=f column blocks
#pragma unroll
        for (int kc = 0; kc < 4; ++kc)
            bU[s][kc] = *(const bf16x8*)(UT + (size_t)row * 128 + kc * 32 + q * 8);
    }
}

// ---------------------------------------------------------------------------
// Levels dep 9/8/7: 8*NCT parents (16*NCT children) per block, grid-parallel.
// All variants at (512,2): bU alone is 64 VGPRs, tighter bounds spill.
template<int NCT>
__global__ __launch_bounds__(512, 2) void big_level_k(const uint16_t* __restrict__ wx,
                                                      const uint16_t* __restrict__ UT,
                                                      float* __restrict__ h,
                                                      float* __restrict__ c,
                                                      int dep) {
    __shared__ uint16_t Hc[16 * NCT * 128];
    bf16x8 bU[4][4];
    load_bU(UT, bU);
    const int tid = threadIdx.x;
    const int w = tid >> 6, lane = tid & 63, q = lane >> 4, l15 = lane & 15;
    const int colf = w * 16 + l15;
    int idx0 = blockIdx.x * (8 * NCT);
    int tree = idx0 >> dep;
    int pos0 = idx0 - (tree << dep);
    int np = 1 << dep;
    int vp = tree * MTREE + (np - 1) + pos0;
    int vc = tree * MTREE + (2 * np - 1) + 2 * pos0;

    // scattered wx + child-c loads issued first (latency hides under staging+MFMA)
    float wxg[NCT][2][4];
#pragma unroll
    for (int ct = 0; ct < NCT; ++ct)
#pragma unroll
        for (int j = 0; j < 2; ++j) {
            int pl = ct * 8 + q * 2 + j;
            ushort4 g = *(const ushort4*)(wx + (size_t)(vp + pl) * 512 + colf * 4);
            wxg[ct][j][0] = bf2f(g.x);
            wxg[ct][j][1] = bf2f(g.y);
            wxg[ct][j][2] = bf2f(g.z);
            wxg[ct][j][3] = bf2f(g.w);
        }
    float cch[NCT][4];
#pragma unroll
    for (int ct = 0; ct < NCT; ++ct)
#pragma unroll
        for (int r = 0; r < 4; ++r) {
            int cl = ct * 16 + q * 4 + r;
            cch[ct][r] = c[(size_t)(vc + cl) * 128 + colf];
        }

    // stage 16*NCT child-h rows f32 -> bf16 swizzled
#pragma unroll
    for (int t = 0; t < (16 * NCT * 16 + 511) / 512; ++t) {
        int ci = t * 512 + tid;
        if (ci < 16 * NCT * 16) {
            int row = ci >> 4, cx = ci & 15;
            const float* src = h + (size_t)(vc + row) * 128 + cx * 8;
            float4 f0 = *(const float4*)src;
            float4 f1 = *(const float4*)(src + 4);
            *(uint4*)&Hc[SWZ(row, cx)] = pack_bf8(f0, f1);
        }
    }
    __syncthreads();

    // per-child matvec: NCT child-tiles x 4 gates x 4 k-chunks
    f32x4 acc[NCT][4] = {};
#pragma unroll
    for (int ct = 0; ct < NCT; ++ct) {
        bf16x8 a[4];
#pragma unroll
        for (int kc = 0; kc < 4; ++kc)
            a[kc] = *(const bf16x8*)&Hc[SWZ(ct * 16 + l15, kc * 4 + q)];
#pragma unroll
        for (int s = 0; s < 4; ++s)
#pragma unroll
            for (int kc = 0; kc < 4; ++kc)
                acc[ct][s] = __builtin_amdgcn_mfma_f32_16x16x32_bf16(a[kc], bU[s][kc], acc[ct][s], 0, 0, 0);
    }

    // lane-local epilogue: f per child, pair-sum everything per parent
#pragma unroll
    for (int ct = 0; ct < NCT; ++ct) {
        float fc[4];
#pragma unroll
        for (int r = 0; r < 4; ++r)
            fc[r] = sigmoidf_(acc[ct][3][r] + wxg[ct][r >> 1][3]) * cch[ct][r];
#pragma unroll
        for (int j = 0; j < 2; ++j) {
            int pl = ct * 8 + q * 2 + j;
            float ip = acc[ct][0][2 * j] + acc[ct][0][2 * j + 1] + wxg[ct][j][0];
            float op = acc[ct][1][2 * j] + acc[ct][1][2 * j + 1] + wxg[ct][j][1];
            float up = acc[ct][2][2 * j] + acc[ct][2][2 * j + 1] + wxg[ct][j][2];
            float cn = sigmoidf_(ip) * tanhf_(up) + fc[2 * j] + fc[2 * j + 1];
            float hv = sigmoidf_(op) * tanhf_(cn);
            c[(size_t)(vp + pl) * 128 + colf] = cn;
            h[(size_t)(vp + pl) * 128 + colf] = hv;
        }
    }
}

// ---------------------------------------------------------------------------
// Tail: dep 6..0, one block per tree, 8 groups, one barrier per group.
// h in LDS (Hbuf rows 0..127 / 128..191 alternating), c in LDS CS halves.
// R8: next group's wx (and cglob for gi<2) prefetched during current epilogue.
__global__ __launch_bounds__(512, 1) void tail_k(const uint16_t* __restrict__ wx,
                                                 const uint16_t* __restrict__ UT,
                                                 const float* __restrict__ cglob,
                                                 float* __restrict__ h) {
    __shared__ uint16_t Hbuf[192 * 128];   // 48 KB
    __shared__ float CS[128 * 132];        // 66 KB, stride 132 (2-way-free banks)
    bf16x8 bU[4][4];
    load_bU(UT, bU);
    const int tree = blockIdx.x;
    const int tid = threadIdx.x;
    const int w = tid >> 6, lane = tid & 63, q = lane >> 4, l15 = lane & 15;
    const int colf = w * 16 + l15;
    const int vbase = tree * MTREE;

    // preload group 0's wx and child-c (overlaps the Hbuf staging below)
    float wxg[4][2][4];
    float cgl[4][4];
    {
        const int vp0 = vbase + 63;   // gi=0: dep=6, pos0=0
#pragma unroll
        for (int ct = 0; ct < 4; ++ct)
#pragma unroll
            for (int j = 0; j < 2; ++j) {
                int pl = ct * 8 + q * 2 + j;
                ushort4 g = *(const ushort4*)(wx + (size_t)(vp0 + pl) * 512 + colf * 4);
                wxg[ct][j][0] = bf2f(g.x);
                wxg[ct][j][1] = bf2f(g.y);
                wxg[ct][j][2] = bf2f(g.z);
                wxg[ct][j][3] = bf2f(g.w);
            }
#pragma unroll
        for (int ct = 0; ct < 4; ++ct)
#pragma unroll
            for (int r = 0; r < 4; ++r) {
                int cl = ct * 16 + q * 4 + r;
                cgl[ct][r] = cglob[(size_t)(vbase + 127 + cl) * 128 + colf];
            }
    }

    // stage dep-7 h (tree-local nodes 127..254) into Hbuf rows 0..127
#pragma unroll
    for (int t = 0; t < 4; ++t) {
        int ci = t * 512 + tid;
        int row = ci >> 4, cx = ci & 15;
        const float* src = h + (size_t)(vbase + 127 + row) * 128 + cx * 8;
        float4 f0 = *(const float4*)src;
        float4 f1 = *(const float4*)(src + 4);
        *(uint4*)&Hbuf[SWZ(row, cx)] = pack_bf8(f0, f1);
    }

#pragma unroll 1
    for (int gi = 0; gi < 8; ++gi) {
        const int dep = gi < 2 ? 6 : 7 - gi;
        const int np = 1 << dep;
        const int pos0 = (gi == 1) ? 32 : 0;
        const int P = gi < 3 ? 32 : np;
        const int pL = dep & 1;              // 0 for dep 6,4,2,0
        const int childBase = pL ? 128 : 0;
        const int parBase = pL ? 0 : 128;
        const int csRead = pL ? 0 : 64;
        const int csWrite = pL ? 64 : 0;
        const int vp = vbase + (np - 1) + pos0;
        __syncthreads();

        // child c: prefetched global (gi<2) or CS (below)
        float cch[4][4];
        if (gi < 2) {
#pragma unroll
            for (int ct = 0; ct < 4; ++ct)
#pragma unroll
                for (int r = 0; r < 4; ++r)
                    cch[ct][r] = cgl[ct][r];
        } else {
#pragma unroll
            for (int ct = 0; ct < 4; ++ct)
#pragma unroll
                for (int r = 0; r < 4; ++r) {
                    int cl = ct * 16 + q * 4 + r;
                    cch[ct][r] = CS[(csRead + cl) * 132 + colf];
                }
        }

        // per-child matvec
        f32x4 acc[4][4] = {};
#pragma unroll
        for (int ct = 0; ct < 4; ++ct) {
            bf16x8 a[4];
#pragma unroll
            for (int kc = 0; kc < 4; ++kc) {
                int row = childBase + 2 * pos0 + ct * 16 + l15;
                a[kc] = *(const bf16x8*)&Hbuf[SWZ(row, kc * 4 + q)];
            }
#pragma unroll
            for (int s = 0; s < 4; ++s)
#pragma unroll
                for (int kc = 0; kc < 4; ++kc)
                    acc[ct][s] = __builtin_amdgcn_mfma_f32_16x16x32_bf16(a[kc], bU[s][kc], acc[ct][s], 0, 0, 0);
        }

        // prefetch NEXT group's wx (+cglob) — hides under epilogue VALU+stores
        float wxgn[4][2][4] = {};
        float cgln[4][4] = {};
        if (gi < 7) {
            const int gin = gi + 1;
            const int depn = gin < 2 ? 6 : 7 - gin;
            const int npn = 1 << depn;
            const int pos0n = (gin == 1) ? 32 : 0;
            const int vpn = vbase + (npn - 1) + pos0n;
#pragma unroll
            for (int ct = 0; ct < 4; ++ct)
#pragma unroll
                for (int j = 0; j < 2; ++j) {
                    int pl = ct * 8 + q * 2 + j;
                    ushort4 g = *(const ushort4*)(wx + (size_t)(vpn + pl) * 512 + colf * 4);
                    wxgn[ct][j][0] = bf2f(g.x);
                    wxgn[ct][j][1] = bf2f(g.y);
                    wxgn[ct][j][2] = bf2f(g.z);
                    wxgn[ct][j][3] = bf2f(g.w);
                }
            if (gin < 2) {
#pragma unroll
                for (int ct = 0; ct < 4; ++ct)
#pragma unroll
                    for (int r = 0; r < 4; ++r) {
                        int cl = 2 * pos0n + ct * 16 + q * 4 + r;
                        cgln[ct][r] = cglob[(size_t)(vbase + 127 + cl) * 128 + colf];
                    }
            }
        }

        // lane-local epilogue
#pragma unroll
        for (int ct = 0; ct < 4; ++ct) {
            float fc[4];
#pragma unroll
            for (int r = 0; r < 4; ++r)
                fc[r] = sigmoidf_(acc[ct][3][r] + wxg[ct][r >> 1][3]) * cch[ct][r];
#pragma unroll
            for (int j = 0; j < 2; ++j) {
                int pl = ct * 8 + q * 2 + j;
                float ip = acc[ct][0][2 * j] + acc[ct][0][2 * j + 1] + wxg[ct][j][0];
                float op = acc[ct][1][2 * j] + acc[ct][1][2 * j + 1] + wxg[ct][j][1];
                float up = acc[ct][2][2 * j] + acc[ct][2][2 * j + 1] + wxg[ct][j][2];
                float cn = sigmoidf_(ip) * tanhf_(up) + fc[2 * j] + fc[2 * j + 1];
                float hv = sigmoidf_(op) * tanhf_(cn);
                if (pl < P) {
                    h[(size_t)(vp + pl) * 128 + colf] = hv;
                    int row = parBase + pos0 + pl;       // next level's child row
                    Hbuf[row * 128 + (((colf >> 3) ^ (row & 7)) * 8) + (colf & 7)] = f2bf(hv);
                    CS[(csWrite + pos0 + pl) * 132 + colf] = cn;
                }
            }
        }

        // rotate prefetched regs into current (all indices static)
#pragma unroll
        for (int ct = 0; ct < 4; ++ct) {
#pragma unroll
            for (int j = 0; j < 2; ++j)
#pragma unroll
                for (int g = 0; g < 4; ++g)
                    wxg[ct][j][g] = wxgn[ct][j][g];
#pragma unroll
            for (int r = 0; r < 4; ++r)
                cgl[ct][r] = cgln[ct][r];
        }
    }
}

// ---------------------------------------------------------------------------
extern "C" void kernel_launch(void* const* d_in, const int* in_sizes, int n_in,
                              void* d_out, int out_size, void* d_ws, size_t ws_size,
                              hipStream_t stream) {
    const float* features = (const float*)d_in[0];
    const float* W_iou    = (const float*)d_in[1];
    const float* b_iou    = (const float*)d_in[2];
    const float* U_iou    = (const float*)d_in[3];
    const float* W_f      = (const float*)d_in[4];
    const float* b_f      = (const float*)d_in[5];
    const float* U_f      = (const float*)d_in[6];
    float* h = (float*)d_out;

    char* wp = (char*)d_ws;
    uint16_t* wx    = (uint16_t*)wp; wp += (size_t)NNODES * 512 * 2;
    float*    c     = (float*)wp;    wp += (size_t)NNODES * 128 * 4;
    uint16_t* WT    = (uint16_t*)wp; wp += 512 * 128 * 2;
    uint16_t* UT    = (uint16_t*)wp; wp += 512 * 128 * 2;
    float*    biasS = (float*)wp;    wp += 512 * 4;

    hipLaunchKernelGGL(prep_k, dim3(1025), dim3(128), 0, stream,
                       W_iou, W_f, U_iou, U_f, b_iou, b_f, WT, UT, biasS);
    hipLaunchKernelGGL(gemm_leaf_k, dim3(256), dim3(512), 0, stream,
                       features, WT, biasS, wx, h, c);
    hipLaunchKernelGGL((big_level_k<4>), dim3(512), dim3(512), 0, stream, wx, UT, h, c, 9);
    hipLaunchKernelGGL((big_level_k<2>), dim3(512), dim3(512), 0, stream, wx, UT, h, c, 8);
    hipLaunchKernelGGL((big_level_k<1>), dim3(512), dim3(512), 0, stream, wx, UT, h, c, 7);
    hipLaunchKernelGGL(tail_k, dim3(32), dim3(512), 0, stream, wx, UT, c, h);
}

// Round 3
// 201.694 us; speedup vs baseline: 1.2047x; 1.2047x over previous
//
#include <hip/hip_runtime.h>
#include <math.h>
#include <stdint.h>

// TreeLSTM, 32 complete binary trees depth 10, heap order, d=128.
// R9: post-mortem R8: persistent pipeline (grid 256, depth-1 ILP) cannot hide
//     900cy HBM latency with 8 waves/CU; reverted gemm_leaf to R6 structure
//     (grid 1024, TLP from co-resident blocks). New: (1) v_cvt_pk_bf16_f32
//     for ALL f32->bf16 (1 instr/2 vals, RNE-identical) — cuts pack/epilogue
//     VALU ~5x; cold F loads issued before L2-warm weight loads.
//     (2) big<4>+big<2>+big<1> fused into one 512-block kernel (fused3_k):
//     each block owns 8 depth-7 nodes -> 16 depth-8 -> 32 depth-9 -> 64 leaf
//     children; h carried bf16 in LDS, c carried f32 in LDS between levels.
//     Kills 25 MB c9/c8 writes + 50 MB h9/c9/h8/c8 re-reads + 2 launches.

#define NTREES 32
#define MTREE 2047
#define NNODES (NTREES * MTREE)   // 65504

typedef __attribute__((ext_vector_type(8))) short bf16x8;
typedef __attribute__((ext_vector_type(4))) float f32x4;

__device__ __forceinline__ float sigmoidf_(float x) {
    return 1.0f / (1.0f + __expf(-x));
}
__device__ __forceinline__ float tanhf_(float x) {
    x = fminf(fmaxf(x, -10.0f), 10.0f);
    float e = __expf(2.0f * x);
    return (e - 1.0f) / (e + 1.0f);
}
__device__ __forceinline__ float bf2f(uint16_t b) {
    union { uint32_t u; float f; } v; v.u = ((uint32_t)b) << 16; return v.f;
}
// HW packed f32->bf16 (RNE, same as the old bit-twiddle, 1 instr per pair)
__device__ __forceinline__ uint32_t cvtpk(float lo, float hi) {
    uint32_t r;
    asm("v_cvt_pk_bf16_f32 %0, %1, %2" : "=v"(r) : "v"(lo), "v"(hi));
    return r;
}
__device__ __forceinline__ uint16_t f2bf1(float f) {
    return (uint16_t)cvtpk(f, f);
}
__device__ __forceinline__ uint4 pack_bf8(float4 a, float4 b) {
    uint4 r;
    r.x = cvtpk(a.x, a.y); r.y = cvtpk(a.z, a.w);
    r.z = cvtpk(b.x, b.y); r.w = cvtpk(b.z, b.w);
    return r;
}

// Swizzled LDS layout: bf16 rows of 128 (16 chunks of 16B), XOR by row&7.
#define SWZ(row, chunk) ((row) * 128 + (((chunk) ^ ((row) & 7)) * 8))

// ---------------------------------------------------------------------------
__global__ __launch_bounds__(128) void prep_k(const float* __restrict__ Wiou,
                                              const float* __restrict__ Wf,
                                              const float* __restrict__ Uiou,
                                              const float* __restrict__ Uf,
                                              const float* __restrict__ biou,
                                              const float* __restrict__ bf,
                                              uint16_t* __restrict__ WT,
                                              uint16_t* __restrict__ UT,
                                              float* __restrict__ biasS) {
    int n = blockIdx.x, k = threadIdx.x;
    if (n < 512) {
        WT[n * 128 + k] = f2bf1(n < 384 ? Wiou[k * 384 + n] : Wf[k * 128 + (n - 384)]);
    } else if (n < 1024) {
        int m = n - 512;
        UT[m * 128 + k] = f2bf1(m < 384 ? Uiou[k * 384 + m] : Uf[k * 128 + (m - 384)]);
    } else {
#pragma unroll
        for (int r = 0; r < 4; ++r) {
            int j = r * 128 + k;
            biasS[j] = j < 384 ? biou[j] : bf[j - 384];
        }
    }
}

// ---------------------------------------------------------------------------
// Fused GEMM + leaf epilogue (R6 structure: grid 1024, one 64-node tile/block).
// wx layout: wx[v*512 + col*4 + gate], gate = {0:i,1:o,2:u,3:f}.
__global__ __launch_bounds__(512, 2) void gemm_leaf_k(const float* __restrict__ F,
                                                      const uint16_t* __restrict__ WT,
                                                      const float* __restrict__ biasS,
                                                      uint16_t* __restrict__ wx,
                                                      float* __restrict__ h,
                                                      float* __restrict__ c) {
    __shared__ uint16_t Fs[64 * 128];
    const int tid = threadIdx.x;
    const int w = tid >> 6, lane = tid & 63, q = lane >> 4, l15 = lane & 15;
    const int n0 = blockIdx.x * 64;
    const int srow = tid >> 4, scx = tid & 15;

    // cold F loads first (HBM latency), both staging rows
    int va = n0 + srow;      va = va < NNODES ? va : NNODES - 1;
    int vb = n0 + 32 + srow; vb = vb < NNODES ? vb : NNODES - 1;
    const float* sa = F + (size_t)va * 128 + scx * 8;
    const float* sb = F + (size_t)vb * 128 + scx * 8;
    float4 a0 = *(const float4*)sa, a1 = *(const float4*)(sa + 4);
    float4 b0 = *(const float4*)sb, b1 = *(const float4*)(sb + 4);

    // L2-warm weights/bias after
    bf16x8 aW[4][4];
    float4 bias4[4];
#pragma unroll
    for (int s = 0; s < 4; ++s) {
        int row = (w + s * 8) * 16 + l15;
#pragma unroll
        for (int kc = 0; kc < 4; ++kc)
            aW[s][kc] = *(const bf16x8*)(WT + (size_t)row * 128 + kc * 32 + q * 8);
        bias4[s] = *(const float4*)(biasS + (w + s * 8) * 16 + q * 4);
    }

    *(uint4*)&Fs[SWZ(srow, scx)]      = pack_bf8(a0, a1);
    *(uint4*)&Fs[SWZ(32 + srow, scx)] = pack_bf8(b0, b1);
    __syncthreads();

#pragma unroll
    for (int nt = 0; nt < 4; ++nt) {
        bf16x8 b[4];
#pragma unroll
        for (int kc = 0; kc < 4; ++kc)
            b[kc] = *(const bf16x8*)&Fs[SWZ(nt * 16 + l15, kc * 4 + q)];
        f32x4 acc[4] = {};
#pragma unroll
        for (int s = 0; s < 4; ++s)
#pragma unroll
            for (int kc = 0; kc < 4; ++kc)
                acc[s] = __builtin_amdgcn_mfma_f32_16x16x32_bf16(aW[s][kc], b[kc], acc[s], 0, 0, 0);

        int node = n0 + nt * 16 + l15;
        bool nvalid = node < NNODES;
        int v = nvalid ? node : NNODES - 1;
        int tree = v / 2047;
        int j = v - tree * 2047;
        bool leaf = j >= 1023;
        float pi[4], po[4], pu[4], pf[4];
#pragma unroll
        for (int r = 0; r < 4; ++r) {
            pi[r] = acc[0][r] + bias4[0][r];
            po[r] = acc[1][r] + bias4[1][r];
            pu[r] = acc[2][r] + bias4[2][r];
            pf[r] = acc[3][r] + bias4[3][r];
        }
        int colb = w * 16 + q * 4;
        if (nvalid && leaf) {
            float cv[4], hv[4];
#pragma unroll
            for (int r = 0; r < 4; ++r) {
                float iv = sigmoidf_(pi[r]);
                float ov = sigmoidf_(po[r]);
                float uv = tanhf_(pu[r]);
                float cn = iv * uv;
                cv[r] = cn;
                hv[r] = ov * tanhf_(cn);
            }
            *(float4*)&c[(size_t)v * 128 + colb] = *(float4*)cv;
            *(float4*)&h[(size_t)v * 128 + colb] = *(float4*)hv;
        }
        if (nvalid && !leaf) {
            uint4 w0, w1;
            w0.x = cvtpk(pi[0], po[0]);
            w0.y = cvtpk(pu[0], pf[0]);
            w0.z = cvtpk(pi[1], po[1]);
            w0.w = cvtpk(pu[1], pf[1]);
            w1.x = cvtpk(pi[2], po[2]);
            w1.y = cvtpk(pu[2], pf[2]);
            w1.z = cvtpk(pi[3], po[3]);
            w1.w = cvtpk(pu[3], pf[3]);
            uint16_t* wr = wx + (size_t)v * 512 + colb * 4;
            *(uint4*)(wr) = w0;
            *(uint4*)(wr + 8) = w1;
        }
    }
}

// ---------------------------------------------------------------------------
__device__ __forceinline__ void load_bU(const uint16_t* __restrict__ UT, bf16x8 bU[4][4]) {
    const int tid = threadIdx.x;
    const int w = tid >> 6, lane = tid & 63, q = lane >> 4, l15 = lane & 15;
#pragma unroll
    for (int s = 0; s < 4; ++s) {
        int row = (w + s * 8) * 16 + l15;   // s: 0=i,1=o,2=u,3=f column blocks
#pragma unroll
        for (int kc = 0; kc < 4; ++kc)
            bU[s][kc] = *(const bf16x8*)(UT + (size_t)row * 128 + kc * 32 + q * 8);
    }
}

template<int NCT>
__device__ __forceinline__ void matvec_lds(const uint16_t* __restrict__ H,
                                           const bf16x8 bU[4][4],
                                           f32x4 acc[NCT][4], int l15, int q) {
#pragma unroll
    for (int ct = 0; ct < NCT; ++ct) {
        bf16x8 a[4];
#pragma unroll
        for (int kc = 0; kc < 4; ++kc)
            a[kc] = *(const bf16x8*)&H[SWZ(ct * 16 + l15, kc * 4 + q)];
#pragma unroll
        for (int s = 0; s < 4; ++s)
#pragma unroll
            for (int kc = 0; kc < 4; ++kc)
                acc[ct][s] = __builtin_amdgcn_mfma_f32_16x16x32_bf16(a[kc], bU[s][kc], acc[ct][s], 0, 0, 0);
    }
}

// ---------------------------------------------------------------------------
// Fused depth-9/8/7: each block owns 8 depth-7 nodes and their full 3-level
// descendant slice (16 d8, 32 d9, 64 leaves). h carried bf16 in LDS, c f32 in
// LDS. Global: reads leaf h/c + wx(all 3 levels); writes h(d9,d8,d7) + c(d7).
__global__ __launch_bounds__(512, 1) void fused3_k(const uint16_t* __restrict__ wx,
                                                   const uint16_t* __restrict__ UT,
                                                   float* __restrict__ h,
                                                   float* __restrict__ c) {
    __shared__ uint16_t HA[64 * 128];   // 16 KB leaf h (bf16 swz)
    __shared__ uint16_t H9[32 * 128];   // 8 KB
    __shared__ uint16_t H8[16 * 128];   // 4 KB
    __shared__ float C9[32 * 132];      // 16.5 KB
    __shared__ float C8[16 * 132];      // 8.25 KB
    bf16x8 bU[4][4];
    load_bU(UT, bU);
    const int tid = threadIdx.x;
    const int w = tid >> 6, lane = tid & 63, q = lane >> 4, l15 = lane & 15;
    const int colf = w * 16 + l15;
    const int tree = blockIdx.x >> 4;
    const int pos0 = (blockIdx.x & 15) * 8;     // depth-7 local base
    const int vbase = tree * MTREE;
    const int v7 = vbase + 127 + pos0;
    const int v8 = vbase + 255 + 2 * pos0;
    const int v9 = vbase + 511 + 4 * pos0;
    const int v10 = vbase + 1023 + 8 * pos0;

    // ---- all scattered global loads up front (hide under staging) ----
    float wxA[4][2][4], wxB[2][2][4], wxC[2][4];
#pragma unroll
    for (int ct = 0; ct < 4; ++ct)
#pragma unroll
        for (int j = 0; j < 2; ++j) {
            int pl = ct * 8 + q * 2 + j;
            ushort4 g = *(const ushort4*)(wx + (size_t)(v9 + pl) * 512 + colf * 4);
            wxA[ct][j][0] = bf2f(g.x); wxA[ct][j][1] = bf2f(g.y);
            wxA[ct][j][2] = bf2f(g.z); wxA[ct][j][3] = bf2f(g.w);
        }
#pragma unroll
    for (int ct = 0; ct < 2; ++ct)
#pragma unroll
        for (int j = 0; j < 2; ++j) {
            int pl = ct * 8 + q * 2 + j;
            ushort4 g = *(const ushort4*)(wx + (size_t)(v8 + pl) * 512 + colf * 4);
            wxB[ct][j][0] = bf2f(g.x); wxB[ct][j][1] = bf2f(g.y);
            wxB[ct][j][2] = bf2f(g.z); wxB[ct][j][3] = bf2f(g.w);
        }
#pragma unroll
    for (int j = 0; j < 2; ++j) {
        int pl = q * 2 + j;
        ushort4 g = *(const ushort4*)(wx + (size_t)(v7 + pl) * 512 + colf * 4);
        wxC[j][0] = bf2f(g.x); wxC[j][1] = bf2f(g.y);
        wxC[j][2] = bf2f(g.z); wxC[j][3] = bf2f(g.w);
    }
    float cchA[4][4];
#pragma unroll
    for (int ct = 0; ct < 4; ++ct)
#pragma unroll
        for (int r = 0; r < 4; ++r) {
            int cl = ct * 16 + q * 4 + r;
            cchA[ct][r] = c[(size_t)(v10 + cl) * 128 + colf];
        }

    // stage 64 leaf-h rows f32 -> bf16 swizzled
#pragma unroll
    for (int t = 0; t < 2; ++t) {
        int ci = t * 512 + tid;
        int row = ci >> 4, cx = ci & 15;
        const float* src = h + (size_t)(v10 + row) * 128 + cx * 8;
        float4 f0 = *(const float4*)src;
        float4 f1 = *(const float4*)(src + 4);
        *(uint4*)&HA[SWZ(row, cx)] = pack_bf8(f0, f1);
    }
    __syncthreads();

    // ---- LEVEL A: 32 depth-9 parents from 64 leaf children ----
    {
        f32x4 acc[4][4] = {};
        matvec_lds<4>(HA, bU, acc, l15, q);
#pragma unroll
        for (int ct = 0; ct < 4; ++ct) {
            float fc[4];
#pragma unroll
            for (int r = 0; r < 4; ++r)
                fc[r] = sigmoidf_(acc[ct][3][r] + wxA[ct][r >> 1][3]) * cchA[ct][r];
#pragma unroll
            for (int j = 0; j < 2; ++j) {
                int pl = ct * 8 + q * 2 + j;
                float ip = acc[ct][0][2 * j] + acc[ct][0][2 * j + 1] + wxA[ct][j][0];
                float op = acc[ct][1][2 * j] + acc[ct][1][2 * j + 1] + wxA[ct][j][1];
                float up = acc[ct][2][2 * j] + acc[ct][2][2 * j + 1] + wxA[ct][j][2];
                float cn = sigmoidf_(ip) * tanhf_(up) + fc[2 * j] + fc[2 * j + 1];
                float hv = sigmoidf_(op) * tanhf_(cn);
                h[(size_t)(v9 + pl) * 128 + colf] = hv;
                H9[pl * 128 + (((colf >> 3) ^ (pl & 7)) * 8) + (colf & 7)] = f2bf1(hv);
                C9[pl * 132 + colf] = cn;
            }
        }
    }
    __syncthreads();

    // ---- LEVEL B: 16 depth-8 parents from 32 depth-9 children (LDS) ----
    {
        float cch[2][4];
#pragma unroll
        for (int ct = 0; ct < 2; ++ct)
#pragma unroll
            for (int r = 0; r < 4; ++r)
                cch[ct][r] = C9[(ct * 16 + q * 4 + r) * 132 + colf];
        f32x4 acc[2][4] = {};
        matvec_lds<2>(H9, bU, acc, l15, q);
#pragma unroll
        for (int ct = 0; ct < 2; ++ct) {
            float fc[4];
#pragma unroll
            for (int r = 0; r < 4; ++r)
                fc[r] = sigmoidf_(acc[ct][3][r] + wxB[ct][r >> 1][3]) * cch[ct][r];
#pragma unroll
            for (int j = 0; j < 2; ++j) {
                int pl = ct * 8 + q * 2 + j;
                float ip = acc[ct][0][2 * j] + acc[ct][0][2 * j + 1] + wxB[ct][j][0];
                float op = acc[ct][1][2 * j] + acc[ct][1][2 * j + 1] + wxB[ct][j][1];
                float up = acc[ct][2][2 * j] + acc[ct][2][2 * j + 1] + wxB[ct][j][2];
                float cn = sigmoidf_(ip) * tanhf_(up) + fc[2 * j] + fc[2 * j + 1];
                float hv = sigmoidf_(op) * tanhf_(cn);
                h[(size_t)(v8 + pl) * 128 + colf] = hv;
                H8[pl * 128 + (((colf >> 3) ^ (pl & 7)) * 8) + (colf & 7)] = f2bf1(hv);
                C8[pl * 132 + colf] = cn;
            }
        }
    }
    __syncthreads();

    // ---- LEVEL C: 8 depth-7 parents from 16 depth-8 children (LDS) ----
    {
        float cch[4];
#pragma unroll
        for (int r = 0; r < 4; ++r)
            cch[r] = C8[(q * 4 + r) * 132 + colf];
        f32x4 acc[1][4] = {};
        matvec_lds<1>(H8, bU, acc, l15, q);
        float fc[4];
#pragma unroll
        for (int r = 0; r < 4; ++r)
            fc[r] = sigmoidf_(acc[0][3][r] + wxC[r >> 1][3]) * cch[r];
#pragma unroll
        for (int j = 0; j < 2; ++j) {
            int pl = q * 2 + j;
            float ip = acc[0][0][2 * j] + acc[0][0][2 * j + 1] + wxC[j][0];
            float op = acc[0][1][2 * j] + acc[0][1][2 * j + 1] + wxC[j][1];
            float up = acc[0][2][2 * j] + acc[0][2][2 * j + 1] + wxC[j][2];
            float cn = sigmoidf_(ip) * tanhf_(up) + fc[2 * j] + fc[2 * j + 1];
            float hv = sigmoidf_(op) * tanhf_(cn);
            h[(size_t)(v7 + pl) * 128 + colf] = hv;
            c[(size_t)(v7 + pl) * 128 + colf] = cn;   // tail reads c(d7)
        }
    }
}

// ---------------------------------------------------------------------------
// Tail: dep 6..0, one block per tree, 8 groups, one barrier per group.
// h in LDS (Hbuf rows 0..127 / 128..191 alternating), c in LDS CS halves.
// Next group's wx (and cglob for gi<2) prefetched during current epilogue.
__global__ __launch_bounds__(512, 1) void tail_k(const uint16_t* __restrict__ wx,
                                                 const uint16_t* __restrict__ UT,
                                                 const float* __restrict__ cglob,
                                                 float* __restrict__ h) {
    __shared__ uint16_t Hbuf[192 * 128];   // 48 KB
    __shared__ float CS[128 * 132];        // 66 KB, stride 132 (2-way-free banks)
    bf16x8 bU[4][4];
    load_bU(UT, bU);
    const int tree = blockIdx.x;
    const int tid = threadIdx.x;
    const int w = tid >> 6, lane = tid & 63, q = lane >> 4, l15 = lane & 15;
    const int colf = w * 16 + l15;
    const int vbase = tree * MTREE;

    // preload group 0's wx and child-c (overlaps the Hbuf staging below)
    float wxg[4][2][4];
    float cgl[4][4];
    {
        const int vp0 = vbase + 63;   // gi=0: dep=6, pos0=0
#pragma unroll
        for (int ct = 0; ct < 4; ++ct)
#pragma unroll
            for (int j = 0; j < 2; ++j) {
                int pl = ct * 8 + q * 2 + j;
                ushort4 g = *(const ushort4*)(wx + (size_t)(vp0 + pl) * 512 + colf * 4);
                wxg[ct][j][0] = bf2f(g.x);
                wxg[ct][j][1] = bf2f(g.y);
                wxg[ct][j][2] = bf2f(g.z);
                wxg[ct][j][3] = bf2f(g.w);
            }
#pragma unroll
        for (int ct = 0; ct < 4; ++ct)
#pragma unroll
            for (int r = 0; r < 4; ++r) {
                int cl = ct * 16 + q * 4 + r;
                cgl[ct][r] = cglob[(size_t)(vbase + 127 + cl) * 128 + colf];
            }
    }

    // stage dep-7 h (tree-local nodes 127..254) into Hbuf rows 0..127
#pragma unroll
    for (int t = 0; t < 4; ++t) {
        int ci = t * 512 + tid;
        int row = ci >> 4, cx = ci & 15;
        const float* src = h + (size_t)(vbase + 127 + row) * 128 + cx * 8;
        float4 f0 = *(const float4*)src;
        float4 f1 = *(const float4*)(src + 4);
        *(uint4*)&Hbuf[SWZ(row, cx)] = pack_bf8(f0, f1);
    }

#pragma unroll 1
    for (int gi = 0; gi < 8; ++gi) {
        const int dep = gi < 2 ? 6 : 7 - gi;
        const int np = 1 << dep;
        const int pos0 = (gi == 1) ? 32 : 0;
        const int P = gi < 3 ? 32 : np;
        const int pL = dep & 1;              // 0 for dep 6,4,2,0
        const int childBase = pL ? 128 : 0;
        const int parBase = pL ? 0 : 128;
        const int csRead = pL ? 0 : 64;
        const int csWrite = pL ? 64 : 0;
        const int vp = vbase + (np - 1) + pos0;
        __syncthreads();

        // child c: prefetched global (gi<2) or CS (below)
        float cch[4][4];
        if (gi < 2) {
#pragma unroll
            for (int ct = 0; ct < 4; ++ct)
#pragma unroll
                for (int r = 0; r < 4; ++r)
                    cch[ct][r] = cgl[ct][r];
        } else {
#pragma unroll
            for (int ct = 0; ct < 4; ++ct)
#pragma unroll
                for (int r = 0; r < 4; ++r) {
                    int cl = ct * 16 + q * 4 + r;
                    cch[ct][r] = CS[(csRead + cl) * 132 + colf];
                }
        }

        // per-child matvec
        f32x4 acc[4][4] = {};
#pragma unroll
        for (int ct = 0; ct < 4; ++ct) {
            bf16x8 a[4];
#pragma unroll
            for (int kc = 0; kc < 4; ++kc) {
                int row = childBase + 2 * pos0 + ct * 16 + l15;
                a[kc] = *(const bf16x8*)&Hbuf[SWZ(row, kc * 4 + q)];
            }
#pragma unroll
            for (int s = 0; s < 4; ++s)
#pragma unroll
                for (int kc = 0; kc < 4; ++kc)
                    acc[ct][s] = __builtin_amdgcn_mfma_f32_16x16x32_bf16(a[kc], bU[s][kc], acc[ct][s], 0, 0, 0);
        }

        // prefetch NEXT group's wx (+cglob) — hides under epilogue VALU+stores
        float wxgn[4][2][4] = {};
        float cgln[4][4] = {};
        if (gi < 7) {
            const int gin = gi + 1;
            const int depn = gin < 2 ? 6 : 7 - gin;
            const int npn = 1 << depn;
            const int pos0n = (gin == 1) ? 32 : 0;
            const int vpn = vbase + (npn - 1) + pos0n;
#pragma unroll
            for (int ct = 0; ct < 4; ++ct)
#pragma unroll
                for (int j = 0; j < 2; ++j) {
                    int pl = ct * 8 + q * 2 + j;
                    ushort4 g = *(const ushort4*)(wx + (size_t)(vpn + pl) * 512 + colf * 4);
                    wxgn[ct][j][0] = bf2f(g.x);
                    wxgn[ct][j][1] = bf2f(g.y);
                    wxgn[ct][j][2] = bf2f(g.z);
                    wxgn[ct][j][3] = bf2f(g.w);
                }
            if (gin < 2) {
#pragma unroll
                for (int ct = 0; ct < 4; ++ct)
#pragma unroll
                    for (int r = 0; r < 4; ++r) {
                        int cl = 2 * pos0n + ct * 16 + q * 4 + r;
                        cgln[ct][r] = cglob[(size_t)(vbase + 127 + cl) * 128 + colf];
                    }
            }
        }

        // lane-local epilogue
#pragma unroll
        for (int ct = 0; ct < 4; ++ct) {
            float fc[4];
#pragma unroll
            for (int r = 0; r < 4; ++r)
                fc[r] = sigmoidf_(acc[ct][3][r] + wxg[ct][r >> 1][3]) * cch[ct][r];
#pragma unroll
            for (int j = 0; j < 2; ++j) {
                int pl = ct * 8 + q * 2 + j;
                float ip = acc[ct][0][2 * j] + acc[ct][0][2 * j + 1] + wxg[ct][j][0];
                float op = acc[ct][1][2 * j] + acc[ct][1][2 * j + 1] + wxg[ct][j][1];
                float up = acc[ct][2][2 * j] + acc[ct][2][2 * j + 1] + wxg[ct][j][2];
                float cn = sigmoidf_(ip) * tanhf_(up) + fc[2 * j] + fc[2 * j + 1];
                float hv = sigmoidf_(op) * tanhf_(cn);
                if (pl < P) {
                    h[(size_t)(vp + pl) * 128 + colf] = hv;
                    int row = parBase + pos0 + pl;       // next level's child row
                    Hbuf[row * 128 + (((colf >> 3) ^ (row & 7)) * 8) + (colf & 7)] = f2bf1(hv);
                    CS[(csWrite + pos0 + pl) * 132 + colf] = cn;
                }
            }
        }

        // rotate prefetched regs into current (all indices static)
#pragma unroll
        for (int ct = 0; ct < 4; ++ct) {
#pragma unroll
            for (int j = 0; j < 2; ++j)
#pragma unroll
                for (int g = 0; g < 4; ++g)
                    wxg[ct][j][g] = wxgn[ct][j][g];
#pragma unroll
            for (int r = 0; r < 4; ++r)
                cgl[ct][r] = cgln[ct][r];
        }
    }
}

// ---------------------------------------------------------------------------
extern "C" void kernel_launch(void* const* d_in, const int* in_sizes, int n_in,
                              void* d_out, int out_size, void* d_ws, size_t ws_size,
                              hipStream_t stream) {
    const float* features = (const float*)d_in[0];
    const float* W_iou    = (const float*)d_in[1];
    const float* b_iou    = (const float*)d_in[2];
    const float* U_iou    = (const float*)d_in[3];
    const float* W_f      = (const float*)d_in[4];
    const float* b_f      = (const float*)d_in[5];
    const float* U_f      = (const float*)d_in[6];
    float* h = (float*)d_out;

    char* wp = (char*)d_ws;
    uint16_t* wx    = (uint16_t*)wp; wp += (size_t)NNODES * 512 * 2;
    float*    c     = (float*)wp;    wp += (size_t)NNODES * 128 * 4;
    uint16_t* WT    = (uint16_t*)wp; wp += 512 * 128 * 2;
    uint16_t* UT    = (uint16_t*)wp; wp += 512 * 128 * 2;
    float*    biasS = (float*)wp;    wp += 512 * 4;

    hipLaunchKernelGGL(prep_k, dim3(1025), dim3(128), 0, stream,
                       W_iou, W_f, U_iou, U_f, b_iou, b_f, WT, UT, biasS);
    hipLaunchKernelGGL(gemm_leaf_k, dim3(1024), dim3(512), 0, stream,
                       features, WT, biasS, wx, h, c);
    hipLaunchKernelGGL(fused3_k, dim3(512), dim3(512), 0, stream, wx, UT, h, c);
    hipLaunchKernelGGL(tail_k, dim3(32), dim3(512), 0, stream, wx, UT, c, h);
}

// Round 5
// 198.682 us; speedup vs baseline: 1.2230x; 1.0152x over previous
//
#include <hip/hip_runtime.h>
#include <math.h>
#include <stdint.h>

// TreeLSTM, 32 complete binary trees depth 10, heap order, d=128.
// R10 (resubmit; R4 bench was an infra failure, kernel never ran):
//      tail_k was the top kernel (45us) at 2.4% occupancy / 94% stall —
//      serial-chain bound, with __syncthreads() vmcnt(0)-draining prefetch
//      loads + store-acks into the chain 8 times. Fixes:
//      (1) raw barriers (lgkmcnt(0) + s_barrier + sched_barrier(0)) in
//          tail/fused3/gemm — stores & prefetch stay in flight;
//      (2) no barrier between gi0/gi1 (both dep6, disjoint LDS regions);
//      (3) per-group matvec sized to the level: nct = 4,4,4,2,1,1,1,1
//          (wave-uniform predication, static reg indices).

#define NTREES 32
#define MTREE 2047
#define NNODES (NTREES * MTREE)   // 65504

typedef __attribute__((ext_vector_type(8))) short bf16x8;
typedef __attribute__((ext_vector_type(4))) float f32x4;

__device__ __forceinline__ float sigmoidf_(float x) {
    return 1.0f / (1.0f + __expf(-x));
}
__device__ __forceinline__ float tanhf_(float x) {
    x = fminf(fmaxf(x, -10.0f), 10.0f);
    float e = __expf(2.0f * x);
    return (e - 1.0f) / (e + 1.0f);
}
__device__ __forceinline__ float bf2f(uint16_t b) {
    union { uint32_t u; float f; } v; v.u = ((uint32_t)b) << 16; return v.f;
}
// HW packed f32->bf16 (RNE), 1 instr per pair
__device__ __forceinline__ uint32_t cvtpk(float lo, float hi) {
    uint32_t r;
    asm("v_cvt_pk_bf16_f32 %0, %1, %2" : "=v"(r) : "v"(lo), "v"(hi));
    return r;
}
__device__ __forceinline__ uint16_t f2bf1(float f) {
    return (uint16_t)cvtpk(f, f);
}
__device__ __forceinline__ uint4 pack_bf8(float4 a, float4 b) {
    uint4 r;
    r.x = cvtpk(a.x, a.y); r.y = cvtpk(a.z, a.w);
    r.z = cvtpk(b.x, b.y); r.w = cvtpk(b.z, b.w);
    return r;
}

// raw workgroup barrier: LDS visibility only; global loads/stores stay in flight
__device__ __forceinline__ void lds_barrier() {
    asm volatile("s_waitcnt lgkmcnt(0)" ::: "memory");
    __builtin_amdgcn_s_barrier();
    __builtin_amdgcn_sched_barrier(0);
}

// Swizzled LDS layout: bf16 rows of 128 (16 chunks of 16B), XOR by row&7.
#define SWZ(row, chunk) ((row) * 128 + (((chunk) ^ ((row) & 7)) * 8))

// ---------------------------------------------------------------------------
__global__ __launch_bounds__(128) void prep_k(const float* __restrict__ Wiou,
                                              const float* __restrict__ Wf,
                                              const float* __restrict__ Uiou,
                                              const float* __restrict__ Uf,
                                              const float* __restrict__ biou,
                                              const float* __restrict__ bf,
                                              uint16_t* __restrict__ WT,
                                              uint16_t* __restrict__ UT,
                                              float* __restrict__ biasS) {
    int n = blockIdx.x, k = threadIdx.x;
    if (n < 512) {
        WT[n * 128 + k] = f2bf1(n < 384 ? Wiou[k * 384 + n] : Wf[k * 128 + (n - 384)]);
    } else if (n < 1024) {
        int m = n - 512;
        UT[m * 128 + k] = f2bf1(m < 384 ? Uiou[k * 384 + m] : Uf[k * 128 + (m - 384)]);
    } else {
#pragma unroll
        for (int r = 0; r < 4; ++r) {
            int j = r * 128 + k;
            biasS[j] = j < 384 ? biou[j] : bf[j - 384];
        }
    }
}

// ---------------------------------------------------------------------------
// Fused GEMM + leaf epilogue (grid 1024, one 64-node tile/block).
// wx layout: wx[v*512 + col*4 + gate], gate = {0:i,1:o,2:u,3:f}.
__global__ __launch_bounds__(512, 2) void gemm_leaf_k(const float* __restrict__ F,
                                                      const uint16_t* __restrict__ WT,
                                                      const float* __restrict__ biasS,
                                                      uint16_t* __restrict__ wx,
                                                      float* __restrict__ h,
                                                      float* __restrict__ c) {
    __shared__ uint16_t Fs[64 * 128];
    const int tid = threadIdx.x;
    const int w = tid >> 6, lane = tid & 63, q = lane >> 4, l15 = lane & 15;
    const int n0 = blockIdx.x * 64;
    const int srow = tid >> 4, scx = tid & 15;

    // cold F loads first (HBM latency), both staging rows
    int va = n0 + srow;      va = va < NNODES ? va : NNODES - 1;
    int vb = n0 + 32 + srow; vb = vb < NNODES ? vb : NNODES - 1;
    const float* sa = F + (size_t)va * 128 + scx * 8;
    const float* sb = F + (size_t)vb * 128 + scx * 8;
    float4 a0 = *(const float4*)sa, a1 = *(const float4*)(sa + 4);
    float4 b0 = *(const float4*)sb, b1 = *(const float4*)(sb + 4);

    // L2-warm weights/bias after
    bf16x8 aW[4][4];
    float4 bias4[4];
#pragma unroll
    for (int s = 0; s < 4; ++s) {
        int row = (w + s * 8) * 16 + l15;
#pragma unroll
        for (int kc = 0; kc < 4; ++kc)
            aW[s][kc] = *(const bf16x8*)(WT + (size_t)row * 128 + kc * 32 + q * 8);
        bias4[s] = *(const float4*)(biasS + (w + s * 8) * 16 + q * 4);
    }

    *(uint4*)&Fs[SWZ(srow, scx)]      = pack_bf8(a0, a1);
    *(uint4*)&Fs[SWZ(32 + srow, scx)] = pack_bf8(b0, b1);
    lds_barrier();

#pragma unroll
    for (int nt = 0; nt < 4; ++nt) {
        bf16x8 b[4];
#pragma unroll
        for (int kc = 0; kc < 4; ++kc)
            b[kc] = *(const bf16x8*)&Fs[SWZ(nt * 16 + l15, kc * 4 + q)];
        f32x4 acc[4] = {};
#pragma unroll
        for (int s = 0; s < 4; ++s)
#pragma unroll
            for (int kc = 0; kc < 4; ++kc)
                acc[s] = __builtin_amdgcn_mfma_f32_16x16x32_bf16(aW[s][kc], b[kc], acc[s], 0, 0, 0);

        int node = n0 + nt * 16 + l15;
        bool nvalid = node < NNODES;
        int v = nvalid ? node : NNODES - 1;
        int tree = v / 2047;
        int j = v - tree * 2047;
        bool leaf = j >= 1023;
        float pi[4], po[4], pu[4], pf[4];
#pragma unroll
        for (int r = 0; r < 4; ++r) {
            pi[r] = acc[0][r] + bias4[0][r];
            po[r] = acc[1][r] + bias4[1][r];
            pu[r] = acc[2][r] + bias4[2][r];
            pf[r] = acc[3][r] + bias4[3][r];
        }
        int colb = w * 16 + q * 4;
        if (nvalid && leaf) {
            float cv[4], hv[4];
#pragma unroll
            for (int r = 0; r < 4; ++r) {
                float iv = sigmoidf_(pi[r]);
                float ov = sigmoidf_(po[r]);
                float uv = tanhf_(pu[r]);
                float cn = iv * uv;
                cv[r] = cn;
                hv[r] = ov * tanhf_(cn);
            }
            *(float4*)&c[(size_t)v * 128 + colb] = *(float4*)cv;
            *(float4*)&h[(size_t)v * 128 + colb] = *(float4*)hv;
        }
        if (nvalid && !leaf) {
            uint4 w0, w1;
            w0.x = cvtpk(pi[0], po[0]);
            w0.y = cvtpk(pu[0], pf[0]);
            w0.z = cvtpk(pi[1], po[1]);
            w0.w = cvtpk(pu[1], pf[1]);
            w1.x = cvtpk(pi[2], po[2]);
            w1.y = cvtpk(pu[2], pf[2]);
            w1.z = cvtpk(pi[3], po[3]);
            w1.w = cvtpk(pu[3], pf[3]);
            uint16_t* wr = wx + (size_t)v * 512 + colb * 4;
            *(uint4*)(wr) = w0;
            *(uint4*)(wr + 8) = w1;
        }
    }
}

// ---------------------------------------------------------------------------
__device__ __forceinline__ void load_bU(const uint16_t* __restrict__ UT, bf16x8 bU[4][4]) {
    const int tid = threadIdx.x;
    const int w = tid >> 6, lane = tid & 63, q = lane >> 4, l15 = lane & 15;
#pragma unroll
    for (int s = 0; s < 4; ++s) {
        int row = (w + s * 8) * 16 + l15;   // s: 0=i,1=o,2=u,3=f column blocks
#pragma unroll
        for (int kc = 0; kc < 4; ++kc)
            bU[s][kc] = *(const bf16x8*)(UT + (size_t)row * 128 + kc * 32 + q * 8);
    }
}

template<int NCT>
__device__ __forceinline__ void matvec_lds(const uint16_t* __restrict__ H,
                                           const bf16x8 bU[4][4],
                                           f32x4 acc[NCT][4], int l15, int q) {
#pragma unroll
    for (int ct = 0; ct < NCT; ++ct) {
        bf16x8 a[4];
#pragma unroll
        for (int kc = 0; kc < 4; ++kc)
            a[kc] = *(const bf16x8*)&H[SWZ(ct * 16 + l15, kc * 4 + q)];
#pragma unroll
        for (int s = 0; s < 4; ++s)
#pragma unroll
            for (int kc = 0; kc < 4; ++kc)
                acc[ct][s] = __builtin_amdgcn_mfma_f32_16x16x32_bf16(a[kc], bU[s][kc], acc[ct][s], 0, 0, 0);
    }
}

// ---------------------------------------------------------------------------
// Fused depth-9/8/7: each block owns 8 depth-7 nodes and their full 3-level
// descendant slice (16 d8, 32 d9, 64 leaves). h carried bf16 in LDS, c f32 in
// LDS. Global: reads leaf h/c + wx(all 3 levels); writes h(d9,d8,d7) + c(d7).
__global__ __launch_bounds__(512, 1) void fused3_k(const uint16_t* __restrict__ wx,
                                                   const uint16_t* __restrict__ UT,
                                                   float* __restrict__ h,
                                                   float* __restrict__ c) {
    __shared__ uint16_t HA[64 * 128];   // 16 KB leaf h (bf16 swz)
    __shared__ uint16_t H9[32 * 128];   // 8 KB
    __shared__ uint16_t H8[16 * 128];   // 4 KB
    __shared__ float C9[32 * 132];      // 16.5 KB
    __shared__ float C8[16 * 132];      // 8.25 KB
    bf16x8 bU[4][4];
    load_bU(UT, bU);
    const int tid = threadIdx.x;
    const int w = tid >> 6, lane = tid & 63, q = lane >> 4, l15 = lane & 15;
    const int colf = w * 16 + l15;
    const int tree = blockIdx.x >> 4;
    const int pos0 = (blockIdx.x & 15) * 8;     // depth-7 local base
    const int vbase = tree * MTREE;
    const int v7 = vbase + 127 + pos0;
    const int v8 = vbase + 255 + 2 * pos0;
    const int v9 = vbase + 511 + 4 * pos0;
    const int v10 = vbase + 1023 + 8 * pos0;

    // ---- all scattered global loads up front (hide under staging) ----
    float wxA[4][2][4], wxB[2][2][4], wxC[2][4];
#pragma unroll
    for (int ct = 0; ct < 4; ++ct)
#pragma unroll
        for (int j = 0; j < 2; ++j) {
            int pl = ct * 8 + q * 2 + j;
            ushort4 g = *(const ushort4*)(wx + (size_t)(v9 + pl) * 512 + colf * 4);
            wxA[ct][j][0] = bf2f(g.x); wxA[ct][j][1] = bf2f(g.y);
            wxA[ct][j][2] = bf2f(g.z); wxA[ct][j][3] = bf2f(g.w);
        }
#pragma unroll
    for (int ct = 0; ct < 2; ++ct)
#pragma unroll
        for (int j = 0; j < 2; ++j) {
            int pl = ct * 8 + q * 2 + j;
            ushort4 g = *(const ushort4*)(wx + (size_t)(v8 + pl) * 512 + colf * 4);
            wxB[ct][j][0] = bf2f(g.x); wxB[ct][j][1] = bf2f(g.y);
            wxB[ct][j][2] = bf2f(g.z); wxB[ct][j][3] = bf2f(g.w);
        }
#pragma unroll
    for (int j = 0; j < 2; ++j) {
        int pl = q * 2 + j;
        ushort4 g = *(const ushort4*)(wx + (size_t)(v7 + pl) * 512 + colf * 4);
        wxC[j][0] = bf2f(g.x); wxC[j][1] = bf2f(g.y);
        wxC[j][2] = bf2f(g.z); wxC[j][3] = bf2f(g.w);
    }
    float cchA[4][4];
#pragma unroll
    for (int ct = 0; ct < 4; ++ct)
#pragma unroll
        for (int r = 0; r < 4; ++r) {
            int cl = ct * 16 + q * 4 + r;
            cchA[ct][r] = c[(size_t)(v10 + cl) * 128 + colf];
        }

    // stage 64 leaf-h rows f32 -> bf16 swizzled
#pragma unroll
    for (int t = 0; t < 2; ++t) {
        int ci = t * 512 + tid;
        int row = ci >> 4, cx = ci & 15;
        const float* src = h + (size_t)(v10 + row) * 128 + cx * 8;
        float4 f0 = *(const float4*)src;
        float4 f1 = *(const float4*)(src + 4);
        *(uint4*)&HA[SWZ(row, cx)] = pack_bf8(f0, f1);
    }
    lds_barrier();

    // ---- LEVEL A: 32 depth-9 parents from 64 leaf children ----
    {
        f32x4 acc[4][4] = {};
        matvec_lds<4>(HA, bU, acc, l15, q);
#pragma unroll
        for (int ct = 0; ct < 4; ++ct) {
            float fc[4];
#pragma unroll
            for (int r = 0; r < 4; ++r)
                fc[r] = sigmoidf_(acc[ct][3][r] + wxA[ct][r >> 1][3]) * cchA[ct][r];
#pragma unroll
            for (int j = 0; j < 2; ++j) {
                int pl = ct * 8 + q * 2 + j;
                float ip = acc[ct][0][2 * j] + acc[ct][0][2 * j + 1] + wxA[ct][j][0];
                float op = acc[ct][1][2 * j] + acc[ct][1][2 * j + 1] + wxA[ct][j][1];
                float up = acc[ct][2][2 * j] + acc[ct][2][2 * j + 1] + wxA[ct][j][2];
                float cn = sigmoidf_(ip) * tanhf_(up) + fc[2 * j] + fc[2 * j + 1];
                float hv = sigmoidf_(op) * tanhf_(cn);
                h[(size_t)(v9 + pl) * 128 + colf] = hv;
                H9[pl * 128 + (((colf >> 3) ^ (pl & 7)) * 8) + (colf & 7)] = f2bf1(hv);
                C9[pl * 132 + colf] = cn;
            }
        }
    }
    lds_barrier();

    // ---- LEVEL B: 16 depth-8 parents from 32 depth-9 children (LDS) ----
    {
        float cch[2][4];
#pragma unroll
        for (int ct = 0; ct < 2; ++ct)
#pragma unroll
            for (int r = 0; r < 4; ++r)
                cch[ct][r] = C9[(ct * 16 + q * 4 + r) * 132 + colf];
        f32x4 acc[2][4] = {};
        matvec_lds<2>(H9, bU, acc, l15, q);
#pragma unroll
        for (int ct = 0; ct < 2; ++ct) {
            float fc[4];
#pragma unroll
            for (int r = 0; r < 4; ++r)
                fc[r] = sigmoidf_(acc[ct][3][r] + wxB[ct][r >> 1][3]) * cch[ct][r];
#pragma unroll
            for (int j = 0; j < 2; ++j) {
                int pl = ct * 8 + q * 2 + j;
                float ip = acc[ct][0][2 * j] + acc[ct][0][2 * j + 1] + wxB[ct][j][0];
                float op = acc[ct][1][2 * j] + acc[ct][1][2 * j + 1] + wxB[ct][j][1];
                float up = acc[ct][2][2 * j] + acc[ct][2][2 * j + 1] + wxB[ct][j][2];
                float cn = sigmoidf_(ip) * tanhf_(up) + fc[2 * j] + fc[2 * j + 1];
                float hv = sigmoidf_(op) * tanhf_(cn);
                h[(size_t)(v8 + pl) * 128 + colf] = hv;
                H8[pl * 128 + (((colf >> 3) ^ (pl & 7)) * 8) + (colf & 7)] = f2bf1(hv);
                C8[pl * 132 + colf] = cn;
            }
        }
    }
    lds_barrier();

    // ---- LEVEL C: 8 depth-7 parents from 16 depth-8 children (LDS) ----
    {
        float cch[4];
#pragma unroll
        for (int r = 0; r < 4; ++r)
            cch[r] = C8[(q * 4 + r) * 132 + colf];
        f32x4 acc[1][4] = {};
        matvec_lds<1>(H8, bU, acc, l15, q);
        float fc[4];
#pragma unroll
        for (int r = 0; r < 4; ++r)
            fc[r] = sigmoidf_(acc[0][3][r] + wxC[r >> 1][3]) * cch[r];
#pragma unroll
        for (int j = 0; j < 2; ++j) {
            int pl = q * 2 + j;
            float ip = acc[0][0][2 * j] + acc[0][0][2 * j + 1] + wxC[j][0];
            float op = acc[0][1][2 * j] + acc[0][1][2 * j + 1] + wxC[j][1];
            float up = acc[0][2][2 * j] + acc[0][2][2 * j + 1] + wxC[j][2];
            float cn = sigmoidf_(ip) * tanhf_(up) + fc[2 * j] + fc[2 * j + 1];
            float hv = sigmoidf_(op) * tanhf_(cn);
            h[(size_t)(v7 + pl) * 128 + colf] = hv;
            c[(size_t)(v7 + pl) * 128 + colf] = cn;   // tail reads c(d7)
        }
    }
}

// ---------------------------------------------------------------------------
// Tail: dep 6..0, one block per tree. Raw LDS barriers only (no vmcnt drain);
// no barrier between the two dep-6 groups (disjoint LDS); matvec width nct
// scales with level: 4,4,4,2,1,1,1,1.
__global__ __launch_bounds__(512, 1) void tail_k(const uint16_t* __restrict__ wx,
                                                 const uint16_t* __restrict__ UT,
                                                 const float* __restrict__ cglob,
                                                 float* __restrict__ h) {
    __shared__ uint16_t Hbuf[192 * 128];   // 48 KB
    __shared__ float CS[128 * 132];        // 66 KB, stride 132 (2-way-free banks)
    bf16x8 bU[4][4];
    load_bU(UT, bU);
    const int tree = blockIdx.x;
    const int tid = threadIdx.x;
    const int w = tid >> 6, lane = tid & 63, q = lane >> 4, l15 = lane & 15;
    const int colf = w * 16 + l15;
    const int vbase = tree * MTREE;

    // preload group 0's wx and child-c (overlaps the Hbuf staging below)
    float wxg[4][2][4];
    float cgl[4][4];
    {
        const int vp0 = vbase + 63;   // gi=0: dep=6, pos0=0
#pragma unroll
        for (int ct = 0; ct < 4; ++ct)
#pragma unroll
            for (int j = 0; j < 2; ++j) {
                int pl = ct * 8 + q * 2 + j;
                ushort4 g = *(const ushort4*)(wx + (size_t)(vp0 + pl) * 512 + colf * 4);
                wxg[ct][j][0] = bf2f(g.x);
                wxg[ct][j][1] = bf2f(g.y);
                wxg[ct][j][2] = bf2f(g.z);
                wxg[ct][j][3] = bf2f(g.w);
            }
#pragma unroll
        for (int ct = 0; ct < 4; ++ct)
#pragma unroll
            for (int r = 0; r < 4; ++r) {
                int cl = ct * 16 + q * 4 + r;
                cgl[ct][r] = cglob[(size_t)(vbase + 127 + cl) * 128 + colf];
            }
    }

    // stage dep-7 h (tree-local nodes 127..254) into Hbuf rows 0..127
#pragma unroll
    for (int t = 0; t < 4; ++t) {
        int ci = t * 512 + tid;
        int row = ci >> 4, cx = ci & 15;
        const float* src = h + (size_t)(vbase + 127 + row) * 128 + cx * 8;
        float4 f0 = *(const float4*)src;
        float4 f1 = *(const float4*)(src + 4);
        *(uint4*)&Hbuf[SWZ(row, cx)] = pack_bf8(f0, f1);
    }

#pragma unroll 1
    for (int gi = 0; gi < 8; ++gi) {
        const int dep = gi < 2 ? 6 : 7 - gi;
        const int np = 1 << dep;
        const int pos0 = (gi == 1) ? 32 : 0;
        const int P = gi < 3 ? 32 : np;
        const int nct = gi < 3 ? 4 : (gi == 3 ? 2 : 1);  // child tiles actually needed
        const int pL = dep & 1;              // 0 for dep 6,4,2,0
        const int childBase = pL ? 128 : 0;
        const int parBase = pL ? 0 : 128;
        const int csRead = pL ? 0 : 64;
        const int csWrite = pL ? 64 : 0;
        const int vp = vbase + (np - 1) + pos0;
        // gi0/gi1 are both dep-6 and touch disjoint LDS regions: no barrier
        if (gi != 1) lds_barrier();

        // child c: prefetched global (gi<2) or CS (below)
        float cch[4][4];
        if (gi < 2) {
#pragma unroll
            for (int ct = 0; ct < 4; ++ct)
#pragma unroll
                for (int r = 0; r < 4; ++r)
                    cch[ct][r] = cgl[ct][r];
        } else {
#pragma unroll
            for (int ct = 0; ct < 4; ++ct)
                if (ct < nct)
#pragma unroll
                    for (int r = 0; r < 4; ++r) {
                        int cl = ct * 16 + q * 4 + r;
                        cch[ct][r] = CS[(csRead + cl) * 132 + colf];
                    }
        }

        // per-child matvec (only nct child tiles)
        f32x4 acc[4][4] = {};
#pragma unroll
        for (int ct = 0; ct < 4; ++ct) {
            if (ct < nct) {
                bf16x8 a[4];
#pragma unroll
                for (int kc = 0; kc < 4; ++kc) {
                    int row = childBase + 2 * pos0 + ct * 16 + l15;
                    a[kc] = *(const bf16x8*)&Hbuf[SWZ(row, kc * 4 + q)];
                }
#pragma unroll
                for (int s = 0; s < 4; ++s)
#pragma unroll
                    for (int kc = 0; kc < 4; ++kc)
                        acc[ct][s] = __builtin_amdgcn_mfma_f32_16x16x32_bf16(a[kc], bU[s][kc], acc[ct][s], 0, 0, 0);
            }
        }

        // prefetch NEXT group's wx (+cglob) — hides under epilogue VALU+stores
        float wxgn[4][2][4] = {};
        float cgln[4][4] = {};
        if (gi < 7) {
            const int gin = gi + 1;
            const int depn = gin < 2 ? 6 : 7 - gin;
            const int npn = 1 << depn;
            const int pos0n = (gin == 1) ? 32 : 0;
            const int nctn = gin < 3 ? 4 : (gin == 3 ? 2 : 1);
            const int vpn = vbase + (npn - 1) + pos0n;
#pragma unroll
            for (int ct = 0; ct < 4; ++ct)
                if (ct < nctn)
#pragma unroll
                    for (int j = 0; j < 2; ++j) {
                        int pl = ct * 8 + q * 2 + j;
                        ushort4 g = *(const ushort4*)(wx + (size_t)(vpn + pl) * 512 + colf * 4);
                        wxgn[ct][j][0] = bf2f(g.x);
                        wxgn[ct][j][1] = bf2f(g.y);
                        wxgn[ct][j][2] = bf2f(g.z);
                        wxgn[ct][j][3] = bf2f(g.w);
                    }
            if (gin < 2) {
#pragma unroll
                for (int ct = 0; ct < 4; ++ct)
#pragma unroll
                    for (int r = 0; r < 4; ++r) {
                        int cl = 2 * pos0n + ct * 16 + q * 4 + r;
                        cgln[ct][r] = cglob[(size_t)(vbase + 127 + cl) * 128 + colf];
                    }
            }
        }

        // lane-local epilogue
#pragma unroll
        for (int ct = 0; ct < 4; ++ct) {
            if (ct < nct) {
                float fc[4];
#pragma unroll
                for (int r = 0; r < 4; ++r)
                    fc[r] = sigmoidf_(acc[ct][3][r] + wxg[ct][r >> 1][3]) * cch[ct][r];
#pragma unroll
                for (int j = 0; j < 2; ++j) {
                    int pl = ct * 8 + q * 2 + j;
                    float ip = acc[ct][0][2 * j] + acc[ct][0][2 * j + 1] + wxg[ct][j][0];
                    float op = acc[ct][1][2 * j] + acc[ct][1][2 * j + 1] + wxg[ct][j][1];
                    float up = acc[ct][2][2 * j] + acc[ct][2][2 * j + 1] + wxg[ct][j][2];
                    float cn = sigmoidf_(ip) * tanhf_(up) + fc[2 * j] + fc[2 * j + 1];
                    float hv = sigmoidf_(op) * tanhf_(cn);
                    if (pl < P) {
                        h[(size_t)(vp + pl) * 128 + colf] = hv;
                        int row = parBase + pos0 + pl;       // next level's child row
                        Hbuf[row * 128 + (((colf >> 3) ^ (row & 7)) * 8) + (colf & 7)] = f2bf1(hv);
                        CS[(csWrite + pos0 + pl) * 132 + colf] = cn;
                    }
                }
            }
        }

        // rotate prefetched regs into current (all indices static)
#pragma unroll
        for (int ct = 0; ct < 4; ++ct) {
#pragma unroll
            for (int j = 0; j < 2; ++j)
#pragma unroll
                for (int g = 0; g < 4; ++g)
                    wxg[ct][j][g] = wxgn[ct][j][g];
#pragma unroll
            for (int r = 0; r < 4; ++r)
                cgl[ct][r] = cgln[ct][r];
        }
    }
}

// ---------------------------------------------------------------------------
extern "C" void kernel_launch(void* const* d_in, const int* in_sizes, int n_in,
                              void* d_out, int out_size, void* d_ws, size_t ws_size,
                              hipStream_t stream) {
    const float* features = (const float*)d_in[0];
    const float* W_iou    = (const float*)d_in[1];
    const float* b_iou    = (const float*)d_in[2];
    const float* U_iou    = (const float*)d_in[3];
    const float* W_f      = (const float*)d_in[4];
    const float* b_f      = (const float*)d_in[5];
    const float* U_f      = (const float*)d_in[6];
    float* h = (float*)d_out;

    char* wp = (char*)d_ws;
    uint16_t* wx    = (uint16_t*)wp; wp += (size_t)NNODES * 512 * 2;
    float*    c     = (float*)wp;    wp += (size_t)NNODES * 128 * 4;
    uint16_t* WT    = (uint16_t*)wp; wp += 512 * 128 * 2;
    uint16_t* UT    = (uint16_t*)wp; wp += 512 * 128 * 2;
    float*    biasS = (float*)wp;    wp += 512 * 4;

    hipLaunchKernelGGL(prep_k, dim3(1025), dim3(128), 0, stream,
                       W_iou, W_f, U_iou, U_f, b_iou, b_f, WT, UT, biasS);
    hipLaunchKernelGGL(gemm_leaf_k, dim3(1024), dim3(512), 0, stream,
                       features, WT, biasS, wx, h, c);
    hipLaunchKernelGGL(fused3_k, dim3(512), dim3(512), 0, stream, wx, UT, h, c);
    hipLaunchKernelGGL(tail_k, dim3(32), dim3(512), 0, stream, wx, UT, c, h);
}

// Round 6
// 173.913 us; speedup vs baseline: 1.3972x; 1.1424x over previous
//
#include <hip/hip_runtime.h>
#include <math.h>
#include <stdint.h>

// TreeLSTM, 32 complete binary trees depth 10, heap order, d=128.
// R11: tail was serial-VALU bound (40% VALU on its 32 active CUs), not
//      barrier-bound (R10 only -2us). Move the heavy levels out of the
//      serial kernel: fused3 -> fused5 (each of 512 blocks owns 2 d5 nodes
//      and the full 5-level descendant slice; h bf16 + c f32 in LDS).
//      Tail shrinks to 5 small groups (dep 4..0), 29KB LDS.
//      Also: staging loads now issue BEFORE scattered wx prefetch (vmcnt
//      retires in-order; old order made the LDS pack wait on all wx loads).

#define NTREES 32
#define MTREE 2047
#define NNODES (NTREES * MTREE)   // 65504

typedef __attribute__((ext_vector_type(8))) short bf16x8;
typedef __attribute__((ext_vector_type(4))) float f32x4;

__device__ __forceinline__ float sigmoidf_(float x) {
    return 1.0f / (1.0f + __expf(-x));
}
__device__ __forceinline__ float tanhf_(float x) {
    x = fminf(fmaxf(x, -10.0f), 10.0f);
    float e = __expf(2.0f * x);
    return (e - 1.0f) / (e + 1.0f);
}
__device__ __forceinline__ float bf2f(uint16_t b) {
    union { uint32_t u; float f; } v; v.u = ((uint32_t)b) << 16; return v.f;
}
// HW packed f32->bf16 (RNE), 1 instr per pair
__device__ __forceinline__ uint32_t cvtpk(float lo, float hi) {
    uint32_t r;
    asm("v_cvt_pk_bf16_f32 %0, %1, %2" : "=v"(r) : "v"(lo), "v"(hi));
    return r;
}
__device__ __forceinline__ uint16_t f2bf1(float f) {
    return (uint16_t)cvtpk(f, f);
}
__device__ __forceinline__ uint4 pack_bf8(float4 a, float4 b) {
    uint4 r;
    r.x = cvtpk(a.x, a.y); r.y = cvtpk(a.z, a.w);
    r.z = cvtpk(b.x, b.y); r.w = cvtpk(b.z, b.w);
    return r;
}

// raw workgroup barrier: LDS visibility only; global loads/stores stay in flight
__device__ __forceinline__ void lds_barrier() {
    asm volatile("s_waitcnt lgkmcnt(0)" ::: "memory");
    __builtin_amdgcn_s_barrier();
    __builtin_amdgcn_sched_barrier(0);
}

// Swizzled LDS layout: bf16 rows of 128 (16 chunks of 16B), XOR by row&7.
#define SWZ(row, chunk) ((row) * 128 + (((chunk) ^ ((row) & 7)) * 8))

// parent h write into swizzled bf16 LDS row (row base must be ≡0 mod 8)
__device__ __forceinline__ void hwr(uint16_t* buf, int row, int colf, float v) {
    buf[row * 128 + (((colf >> 3) ^ (row & 7)) * 8) + (colf & 7)] = f2bf1(v);
}

__device__ __forceinline__ void wx_unpack(ushort4 g, float o[4]) {
    o[0] = bf2f(g.x); o[1] = bf2f(g.y); o[2] = bf2f(g.z); o[3] = bf2f(g.w);
}

// full gate epilogue for one 16-child tile: acc[4 gates], wxj[2 parents][4
// gates], cch[4 child c]; yields 2 parents' (h, c). fc[r] pairs into parent
// j via child rows 2pl,2pl+1.
__device__ __forceinline__ void gate_epi(const f32x4 acc[4], const float wxj[2][4],
                                         const float cch[4], float hv[2], float cn[2]) {
    float fc[4];
#pragma unroll
    for (int r = 0; r < 4; ++r)
        fc[r] = sigmoidf_(acc[3][r] + wxj[r >> 1][3]) * cch[r];
#pragma unroll
    for (int j = 0; j < 2; ++j) {
        float ip = acc[0][2 * j] + acc[0][2 * j + 1] + wxj[j][0];
        float op = acc[1][2 * j] + acc[1][2 * j + 1] + wxj[j][1];
        float up = acc[2][2 * j] + acc[2][2 * j + 1] + wxj[j][2];
        cn[j] = sigmoidf_(ip) * tanhf_(up) + fc[2 * j] + fc[2 * j + 1];
        hv[j] = sigmoidf_(op) * tanhf_(cn[j]);
    }
}

// ---------------------------------------------------------------------------
__global__ __launch_bounds__(128) void prep_k(const float* __restrict__ Wiou,
                                              const float* __restrict__ Wf,
                                              const float* __restrict__ Uiou,
                                              const float* __restrict__ Uf,
                                              const float* __restrict__ biou,
                                              const float* __restrict__ bf,
                                              uint16_t* __restrict__ WT,
                                              uint16_t* __restrict__ UT,
                                              float* __restrict__ biasS) {
    int n = blockIdx.x, k = threadIdx.x;
    if (n < 512) {
        WT[n * 128 + k] = f2bf1(n < 384 ? Wiou[k * 384 + n] : Wf[k * 128 + (n - 384)]);
    } else if (n < 1024) {
        int m = n - 512;
        UT[m * 128 + k] = f2bf1(m < 384 ? Uiou[k * 384 + m] : Uf[k * 128 + (m - 384)]);
    } else {
#pragma unroll
        for (int r = 0; r < 4; ++r) {
            int j = r * 128 + k;
            biasS[j] = j < 384 ? biou[j] : bf[j - 384];
        }
    }
}

// ---------------------------------------------------------------------------
// Fused GEMM + leaf epilogue (grid 1024, one 64-node tile/block).
// wx layout: wx[v*512 + col*4 + gate], gate = {0:i,1:o,2:u,3:f}.
__global__ __launch_bounds__(512, 2) void gemm_leaf_k(const float* __restrict__ F,
                                                      const uint16_t* __restrict__ WT,
                                                      const float* __restrict__ biasS,
                                                      uint16_t* __restrict__ wx,
                                                      float* __restrict__ h,
                                                      float* __restrict__ c) {
    __shared__ uint16_t Fs[64 * 128];
    const int tid = threadIdx.x;
    const int w = tid >> 6, lane = tid & 63, q = lane >> 4, l15 = lane & 15;
    const int n0 = blockIdx.x * 64;
    const int srow = tid >> 4, scx = tid & 15;

    // cold F loads first (HBM latency), both staging rows
    int va = n0 + srow;      va = va < NNODES ? va : NNODES - 1;
    int vb = n0 + 32 + srow; vb = vb < NNODES ? vb : NNODES - 1;
    const float* sa = F + (size_t)va * 128 + scx * 8;
    const float* sb = F + (size_t)vb * 128 + scx * 8;
    float4 a0 = *(const float4*)sa, a1 = *(const float4*)(sa + 4);
    float4 b0 = *(const float4*)sb, b1 = *(const float4*)(sb + 4);

    // L2-warm weights/bias after
    bf16x8 aW[4][4];
    float4 bias4[4];
#pragma unroll
    for (int s = 0; s < 4; ++s) {
        int row = (w + s * 8) * 16 + l15;
#pragma unroll
        for (int kc = 0; kc < 4; ++kc)
            aW[s][kc] = *(const bf16x8*)(WT + (size_t)row * 128 + kc * 32 + q * 8);
        bias4[s] = *(const float4*)(biasS + (w + s * 8) * 16 + q * 4);
    }

    *(uint4*)&Fs[SWZ(srow, scx)]      = pack_bf8(a0, a1);
    *(uint4*)&Fs[SWZ(32 + srow, scx)] = pack_bf8(b0, b1);
    lds_barrier();

#pragma unroll
    for (int nt = 0; nt < 4; ++nt) {
        bf16x8 b[4];
#pragma unroll
        for (int kc = 0; kc < 4; ++kc)
            b[kc] = *(const bf16x8*)&Fs[SWZ(nt * 16 + l15, kc * 4 + q)];
        f32x4 acc[4] = {};
#pragma unroll
        for (int s = 0; s < 4; ++s)
#pragma unroll
            for (int kc = 0; kc < 4; ++kc)
                acc[s] = __builtin_amdgcn_mfma_f32_16x16x32_bf16(aW[s][kc], b[kc], acc[s], 0, 0, 0);

        int node = n0 + nt * 16 + l15;
        bool nvalid = node < NNODES;
        int v = nvalid ? node : NNODES - 1;
        int tree = v / 2047;
        int j = v - tree * 2047;
        bool leaf = j >= 1023;
        float pi[4], po[4], pu[4], pf[4];
#pragma unroll
        for (int r = 0; r < 4; ++r) {
            pi[r] = acc[0][r] + bias4[0][r];
            po[r] = acc[1][r] + bias4[1][r];
            pu[r] = acc[2][r] + bias4[2][r];
            pf[r] = acc[3][r] + bias4[3][r];
        }
        int colb = w * 16 + q * 4;
        if (nvalid && leaf) {
            float cv[4], hv[4];
#pragma unroll
            for (int r = 0; r < 4; ++r) {
                float iv = sigmoidf_(pi[r]);
                float ov = sigmoidf_(po[r]);
                float uv = tanhf_(pu[r]);
                float cnv = iv * uv;
                cv[r] = cnv;
                hv[r] = ov * tanhf_(cnv);
            }
            *(float4*)&c[(size_t)v * 128 + colb] = *(float4*)cv;
            *(float4*)&h[(size_t)v * 128 + colb] = *(float4*)hv;
        }
        if (nvalid && !leaf) {
            uint4 w0, w1;
            w0.x = cvtpk(pi[0], po[0]);
            w0.y = cvtpk(pu[0], pf[0]);
            w0.z = cvtpk(pi[1], po[1]);
            w0.w = cvtpk(pu[1], pf[1]);
            w1.x = cvtpk(pi[2], po[2]);
            w1.y = cvtpk(pu[2], pf[2]);
            w1.z = cvtpk(pi[3], po[3]);
            w1.w = cvtpk(pu[3], pf[3]);
            uint16_t* wr = wx + (size_t)v * 512 + colb * 4;
            *(uint4*)(wr) = w0;
            *(uint4*)(wr + 8) = w1;
        }
    }
}

// ---------------------------------------------------------------------------
__device__ __forceinline__ void load_bU(const uint16_t* __restrict__ UT, bf16x8 bU[4][4]) {
    const int tid = threadIdx.x;
    const int w = tid >> 6, lane = tid & 63, q = lane >> 4, l15 = lane & 15;
#pragma unroll
    for (int s = 0; s < 4; ++s) {
        int row = (w + s * 8) * 16 + l15;   // s: 0=i,1=o,2=u,3=f column blocks
#pragma unroll
        for (int kc = 0; kc < 4; ++kc)
            bU[s][kc] = *(const bf16x8*)(UT + (size_t)row * 128 + kc * 32 + q * 8);
    }
}

template<int NCT>
__device__ __forceinline__ void matvec_lds(const uint16_t* __restrict__ H,
                                           const bf16x8 bU[4][4],
                                           f32x4 acc[NCT][4], int l15, int q) {
#pragma unroll
    for (int ct = 0; ct < NCT; ++ct) {
        bf16x8 a[4];
#pragma unroll
        for (int kc = 0; kc < 4; ++kc)
            a[kc] = *(const bf16x8*)&H[SWZ(ct * 16 + l15, kc * 4 + q)];
#pragma unroll
        for (int s = 0; s < 4; ++s)
#pragma unroll
            for (int kc = 0; kc < 4; ++kc)
                acc[ct][s] = __builtin_amdgcn_mfma_f32_16x16x32_bf16(a[kc], bU[s][kc], acc[ct][s], 0, 0, 0);
    }
}

// ---------------------------------------------------------------------------
// Fused depth-9..5: each block owns 2 depth-5 nodes + full descendant slice
// (4 d6, 8 d7, 16 d8, 32 d9, 64 leaves). h bf16 + c f32 carried in LDS.
// Global: reads leaf h/c + wx(5 levels); writes h(d9..d5) + c(d5).
__global__ __launch_bounds__(512, 1) void fused5_k(const uint16_t* __restrict__ wx,
                                                   const uint16_t* __restrict__ UT,
                                                   float* __restrict__ h,
                                                   float* __restrict__ c) {
    __shared__ uint16_t HA[64 * 128];   // 16 KB leaf h
    __shared__ uint16_t H9[32 * 128];   // 8 KB
    __shared__ uint16_t H8[16 * 128];   // 4 KB
    __shared__ uint16_t H7[16 * 128];   // 4 KB (8 rows valid)
    __shared__ uint16_t H6[16 * 128];   // 4 KB (4 rows valid)
    __shared__ float C9[32 * 132];      // 16.5 KB
    __shared__ float C8[16 * 132];      // 8.25 KB
    __shared__ float C7[16 * 132];      // 8.25 KB (8 valid)
    __shared__ float C6[16 * 132];      // 8.25 KB (4 valid)
    bf16x8 bU[4][4];
    load_bU(UT, bU);
    const int tid = threadIdx.x;
    const int w = tid >> 6, lane = tid & 63, q = lane >> 4, l15 = lane & 15;
    const int colf = w * 16 + l15;
    const int tree = blockIdx.x >> 4;
    const int pos5 = (blockIdx.x & 15) * 2;     // depth-5 local base (2 nodes)
    const int vbase = tree * MTREE;
    const int v5 = vbase + 31 + pos5;
    const int v6 = vbase + 63 + 2 * pos5;
    const int v7 = vbase + 127 + 4 * pos5;
    const int v8 = vbase + 255 + 8 * pos5;
    const int v9 = vbase + 511 + 16 * pos5;
    const int vL = vbase + 1023 + 32 * pos5;

    // (1) staging loads FIRST (oldest in vmcnt queue -> pack waits only these)
    float4 st0[2], st1[2];
#pragma unroll
    for (int t = 0; t < 2; ++t) {
        int ci = t * 512 + tid;
        int row = ci >> 4, cx = ci & 15;
        const float* src = h + (size_t)(vL + row) * 128 + cx * 8;
        st0[t] = *(const float4*)src;
        st1[t] = *(const float4*)(src + 4);
    }
    // (2) scattered prefetch: wxA/wxB + leaf c
    float wxA[4][2][4], wxB[2][2][4];
#pragma unroll
    for (int ct = 0; ct < 4; ++ct)
#pragma unroll
        for (int j = 0; j < 2; ++j) {
            int pl = ct * 8 + q * 2 + j;
            wx_unpack(*(const ushort4*)(wx + (size_t)(v9 + pl) * 512 + colf * 4), wxA[ct][j]);
        }
#pragma unroll
    for (int ct = 0; ct < 2; ++ct)
#pragma unroll
        for (int j = 0; j < 2; ++j) {
            int pl = ct * 8 + q * 2 + j;
            wx_unpack(*(const ushort4*)(wx + (size_t)(v8 + pl) * 512 + colf * 4), wxB[ct][j]);
        }
    float cchA[4][4];
#pragma unroll
    for (int ct = 0; ct < 4; ++ct)
#pragma unroll
        for (int r = 0; r < 4; ++r) {
            int cl = ct * 16 + q * 4 + r;
            cchA[ct][r] = c[(size_t)(vL + cl) * 128 + colf];
        }
    // (3) pack staging regs -> LDS
#pragma unroll
    for (int t = 0; t < 2; ++t) {
        int ci = t * 512 + tid;
        int row = ci >> 4, cx = ci & 15;
        *(uint4*)&HA[SWZ(row, cx)] = pack_bf8(st0[t], st1[t]);
    }
    lds_barrier();

    // ---- LEVEL A (d9): 32 parents from 64 leaf children ----
    float wxC[2][4], wxD[2][4], wxE[2][4];
    {
        f32x4 acc[4][4] = {};
        matvec_lds<4>(HA, bU, acc, l15, q);
        // prefetch deeper-level wx while A's epilogue runs
#pragma unroll
        for (int j = 0; j < 2; ++j) {
            int pl = q * 2 + j;
            wx_unpack(*(const ushort4*)(wx + (size_t)(v7 + pl) * 512 + colf * 4), wxC[j]);
            wx_unpack(*(const ushort4*)(wx + (size_t)(v6 + pl) * 512 + colf * 4), wxD[j]);
            wx_unpack(*(const ushort4*)(wx + (size_t)(v5 + pl) * 512 + colf * 4), wxE[j]);
        }
#pragma unroll
        for (int ct = 0; ct < 4; ++ct) {
            float hv[2], cn[2];
            gate_epi(acc[ct], wxA[ct], cchA[ct], hv, cn);
#pragma unroll
            for (int j = 0; j < 2; ++j) {
                int pl = ct * 8 + q * 2 + j;
                h[(size_t)(v9 + pl) * 128 + colf] = hv[j];
                hwr(H9, pl, colf, hv[j]);
                C9[pl * 132 + colf] = cn[j];
            }
        }
    }
    lds_barrier();

    // ---- LEVEL B (d8): 16 parents ----
    {
        float cch[2][4];
#pragma unroll
        for (int ct = 0; ct < 2; ++ct)
#pragma unroll
            for (int r = 0; r < 4; ++r)
                cch[ct][r] = C9[(ct * 16 + q * 4 + r) * 132 + colf];
        f32x4 acc[2][4] = {};
        matvec_lds<2>(H9, bU, acc, l15, q);
#pragma unroll
        for (int ct = 0; ct < 2; ++ct) {
            float hv[2], cn[2];
            gate_epi(acc[ct], wxB[ct], cch[ct], hv, cn);
#pragma unroll
            for (int j = 0; j < 2; ++j) {
                int pl = ct * 8 + q * 2 + j;
                h[(size_t)(v8 + pl) * 128 + colf] = hv[j];
                hwr(H8, pl, colf, hv[j]);
                C8[pl * 132 + colf] = cn[j];
            }
        }
    }
    lds_barrier();

    // ---- LEVEL C (d7): 8 parents ----
    {
        float cch[4];
#pragma unroll
        for (int r = 0; r < 4; ++r)
            cch[r] = C8[(q * 4 + r) * 132 + colf];
        f32x4 acc[1][4] = {};
        matvec_lds<1>(H8, bU, acc, l15, q);
        float hv[2], cn[2];
        gate_epi(acc[0], wxC, cch, hv, cn);
#pragma unroll
        for (int j = 0; j < 2; ++j) {
            int pl = q * 2 + j;     // < 8 always valid
            h[(size_t)(v7 + pl) * 128 + colf] = hv[j];
            hwr(H7, pl, colf, hv[j]);
            C7[pl * 132 + colf] = cn[j];
        }
    }
    lds_barrier();

    // ---- LEVEL D (d6): 4 parents (8 valid child rows; rest garbage, discarded) ----
    {
        float cch[4];
#pragma unroll
        for (int r = 0; r < 4; ++r)
            cch[r] = C7[(q * 4 + r) * 132 + colf];
        f32x4 acc[1][4] = {};
        matvec_lds<1>(H7, bU, acc, l15, q);
        float hv[2], cn[2];
        gate_epi(acc[0], wxD, cch, hv, cn);
#pragma unroll
        for (int j = 0; j < 2; ++j) {
            int pl = q * 2 + j;
            if (pl < 4) {
                h[(size_t)(v6 + pl) * 128 + colf] = hv[j];
                hwr(H6, pl, colf, hv[j]);
                C6[pl * 132 + colf] = cn[j];
            }
        }
    }
    lds_barrier();

    // ---- LEVEL E (d5): 2 parents -> global h + c (tail stages these) ----
    {
        float cch[4];
#pragma unroll
        for (int r = 0; r < 4; ++r)
            cch[r] = C6[(q * 4 + r) * 132 + colf];
        f32x4 acc[1][4] = {};
        matvec_lds<1>(H6, bU, acc, l15, q);
        float hv[2], cn[2];
        gate_epi(acc[0], wxE, cch, hv, cn);
#pragma unroll
        for (int j = 0; j < 2; ++j) {
            int pl = q * 2 + j;
            if (pl < 2) {
                h[(size_t)(v5 + pl) * 128 + colf] = hv[j];
                c[(size_t)(v5 + pl) * 128 + colf] = cn[j];
            }
        }
    }
}

// ---------------------------------------------------------------------------
// Tail: dep 4..0 only (5 small groups), one block per tree.
// Hbuf: d5 h staged rows 0..31; parents ping-pong bases 32/0/32/0.
// CS: c ping-pong rows 0..15 / 16..31.
__global__ __launch_bounds__(512, 1) void tail_k(const uint16_t* __restrict__ wx,
                                                 const uint16_t* __restrict__ UT,
                                                 const float* __restrict__ cglob,
                                                 float* __restrict__ h) {
    __shared__ uint16_t Hbuf[48 * 128];   // 12 KB
    __shared__ float CS[32 * 132];        // 16.9 KB
    bf16x8 bU[4][4];
    load_bU(UT, bU);
    const int tree = blockIdx.x;
    const int tid = threadIdx.x;
    const int w = tid >> 6, lane = tid & 63, q = lane >> 4, l15 = lane & 15;
    const int colf = w * 16 + l15;
    const int vbase = tree * MTREE;

    // (1) staging loads first: d5 h = nodes vbase+31..62 (32 rows, 1 pass)
    const int srow = tid >> 4, scx = tid & 15;
    const float* ssrc = h + (size_t)(vbase + 31 + srow) * 128 + scx * 8;
    float4 s0 = *(const float4*)ssrc;
    float4 s1 = *(const float4*)(ssrc + 4);

    // (2) scattered prefetch: all 5 groups' wx + d5 c
    float wx0[2][2][4], wx1[2][4], wx2[2][4], wx3[2][4], wx4[2][4];
#pragma unroll
    for (int ct = 0; ct < 2; ++ct)
#pragma unroll
        for (int j = 0; j < 2; ++j) {
            int pl = ct * 8 + q * 2 + j;
            wx_unpack(*(const ushort4*)(wx + (size_t)(vbase + 15 + pl) * 512 + colf * 4), wx0[ct][j]);
        }
#pragma unroll
    for (int j = 0; j < 2; ++j) {
        int pl = q * 2 + j;
        wx_unpack(*(const ushort4*)(wx + (size_t)(vbase + 7 + pl) * 512 + colf * 4), wx1[j]);
        wx_unpack(*(const ushort4*)(wx + (size_t)(vbase + 3 + pl) * 512 + colf * 4), wx2[j]);
        wx_unpack(*(const ushort4*)(wx + (size_t)(vbase + 1 + pl) * 512 + colf * 4), wx3[j]);
        wx_unpack(*(const ushort4*)(wx + (size_t)(vbase + 0 + pl) * 512 + colf * 4), wx4[j]);
    }
    float cgl[2][4];
#pragma unroll
    for (int ct = 0; ct < 2; ++ct)
#pragma unroll
        for (int r = 0; r < 4; ++r) {
            int cl = ct * 16 + q * 4 + r;
            cgl[ct][r] = cglob[(size_t)(vbase + 31 + cl) * 128 + colf];
        }

    // (3) pack staging -> Hbuf rows 0..31
    *(uint4*)&Hbuf[SWZ(srow, scx)] = pack_bf8(s0, s1);
    lds_barrier();

    // ---- G0: dep4, 16 parents from d5 rows 0..31; parents -> rows 32..47, CS 0..15
    {
        float cch[2][4];
#pragma unroll
        for (int ct = 0; ct < 2; ++ct)
#pragma unroll
            for (int r = 0; r < 4; ++r)
                cch[ct][r] = cgl[ct][r];
        f32x4 acc[2][4] = {};
        matvec_lds<2>(Hbuf, bU, acc, l15, q);
#pragma unroll
        for (int ct = 0; ct < 2; ++ct) {
            float hv[2], cn[2];
            gate_epi(acc[ct], wx0[ct], cch[ct], hv, cn);
#pragma unroll
            for (int j = 0; j < 2; ++j) {
                int pl = ct * 8 + q * 2 + j;      // 0..15, all valid
                h[(size_t)(vbase + 15 + pl) * 128 + colf] = hv[j];
                hwr(Hbuf, 32 + pl, colf, hv[j]);
                CS[pl * 132 + colf] = cn[j];
            }
        }
    }
    lds_barrier();

    // ---- G1: dep3, 8 parents from rows 32..47; parents -> rows 0..7, CS 16..23
    {
        float cch[4];
#pragma unroll
        for (int r = 0; r < 4; ++r)
            cch[r] = CS[(q * 4 + r) * 132 + colf];
        f32x4 acc[1][4] = {};
        matvec_lds<1>(&Hbuf[32 * 128], bU, acc, l15, q);
        float hv[2], cn[2];
        gate_epi(acc[0], wx1, cch, hv, cn);
#pragma unroll
        for (int j = 0; j < 2; ++j) {
            int pl = q * 2 + j;                  // 0..7, all valid
            h[(size_t)(vbase + 7 + pl) * 128 + colf] = hv[j];
            hwr(Hbuf, pl, colf, hv[j]);
            CS[(16 + pl) * 132 + colf] = cn[j];
        }
    }
    lds_barrier();

    // ---- G2: dep2, 4 parents from rows 0..7; parents -> rows 32..35, CS 0..3
    {
        float cch[4];
#pragma unroll
        for (int r = 0; r < 4; ++r)
            cch[r] = CS[(16 + q * 4 + r) * 132 + colf];
        f32x4 acc[1][4] = {};
        matvec_lds<1>(Hbuf, bU, acc, l15, q);
        float hv[2], cn[2];
        gate_epi(acc[0], wx2, cch, hv, cn);
#pragma unroll
        for (int j = 0; j < 2; ++j) {
            int pl = q * 2 + j;
            if (pl < 4) {
                h[(size_t)(vbase + 3 + pl) * 128 + colf] = hv[j];
                hwr(Hbuf, 32 + pl, colf, hv[j]);
                CS[pl * 132 + colf] = cn[j];
            }
        }
    }
    lds_barrier();

    // ---- G3: dep1, 2 parents from rows 32..35; parents -> rows 0..1, CS 16..17
    {
        float cch[4];
#pragma unroll
        for (int r = 0; r < 4; ++r)
            cch[r] = CS[(q * 4 + r) * 132 + colf];
        f32x4 acc[1][4] = {};
        matvec_lds<1>(&Hbuf[32 * 128], bU, acc, l15, q);
        float hv[2], cn[2];
        gate_epi(acc[0], wx3, cch, hv, cn);
#pragma unroll
        for (int j = 0; j < 2; ++j) {
            int pl = q * 2 + j;
            if (pl < 2) {
                h[(size_t)(vbase + 1 + pl) * 128 + colf] = hv[j];
                hwr(Hbuf, pl, colf, hv[j]);
                CS[(16 + pl) * 132 + colf] = cn[j];
            }
        }
    }
    lds_barrier();

    // ---- G4: dep0, root from rows 0..1
    {
        float cch[4];
#pragma unroll
        for (int r = 0; r < 4; ++r)
            cch[r] = CS[(16 + q * 4 + r) * 132 + colf];
        f32x4 acc[1][4] = {};
        matvec_lds<1>(Hbuf, bU, acc, l15, q);
        float hv[2], cn[2];
        gate_epi(acc[0], wx4, cch, hv, cn);
        if (q == 0) {
            // pl = q*2+j == 0 only (j=0)
            h[(size_t)vbase * 128 + colf] = hv[0];
        }
    }
}

// ---------------------------------------------------------------------------
extern "C" void kernel_launch(void* const* d_in, const int* in_sizes, int n_in,
                              void* d_out, int out_size, void* d_ws, size_t ws_size,
                              hipStream_t stream) {
    const float* features = (const float*)d_in[0];
    const float* W_iou    = (const float*)d_in[1];
    const float* b_iou    = (const float*)d_in[2];
    const float* U_iou    = (const float*)d_in[3];
    const float* W_f      = (const float*)d_in[4];
    const float* b_f      = (const float*)d_in[5];
    const float* U_f      = (const float*)d_in[6];
    float* h = (float*)d_out;

    char* wp = (char*)d_ws;
    uint16_t* wx    = (uint16_t*)wp; wp += (size_t)NNODES * 512 * 2;
    float*    c     = (float*)wp;    wp += (size_t)NNODES * 128 * 4;
    uint16_t* WT    = (uint16_t*)wp; wp += 512 * 128 * 2;
    uint16_t* UT    = (uint16_t*)wp; wp += 512 * 128 * 2;
    float*    biasS = (float*)wp;    wp += 512 * 4;

    hipLaunchKernelGGL(prep_k, dim3(1025), dim3(128), 0, stream,
                       W_iou, W_f, U_iou, U_f, b_iou, b_f, WT, UT, biasS);
    hipLaunchKernelGGL(gemm_leaf_k, dim3(1024), dim3(512), 0, stream,
                       features, WT, biasS, wx, h, c);
    hipLaunchKernelGGL(fused5_k, dim3(512), dim3(512), 0, stream, wx, UT, h, c);
    hipLaunchKernelGGL(tail_k, dim3(32), dim3(512), 0, stream, wx, UT, c, h);
}

// Round 7
// 167.567 us; speedup vs baseline: 1.4501x; 1.0379x over previous
//
#include <hip/hip_runtime.h>
#include <math.h>
#include <stdint.h>

// TreeLSTM, 32 complete binary trees depth 10, heap order, d=128.
// R12: gemm_leaf (41.6us, nothing saturated) was round-trip bound: leaf h
//      written then re-read by fused5 (33.5MB), leaf c written+read (33.6MB).
//      Fusion: (1) gemm_int_k = wx for internal nodes only (no div, no leaf
//      branch); (2) fused5L_k = leaf GEMM + epilogue in-block (leaf h -> HA
//      LDS + global out; leaf c -> CA LDS, never global), then the 5-level
//      climb as before. ~67MB round-trip traffic removed.

#define NTREES 32
#define MTREE 2047
#define NNODES (NTREES * MTREE)   // 65504

typedef __attribute__((ext_vector_type(8))) short bf16x8;
typedef __attribute__((ext_vector_type(4))) float f32x4;

__device__ __forceinline__ float sigmoidf_(float x) {
    return 1.0f / (1.0f + __expf(-x));
}
__device__ __forceinline__ float tanhf_(float x) {
    x = fminf(fmaxf(x, -10.0f), 10.0f);
    float e = __expf(2.0f * x);
    return (e - 1.0f) / (e + 1.0f);
}
__device__ __forceinline__ float bf2f(uint16_t b) {
    union { uint32_t u; float f; } v; v.u = ((uint32_t)b) << 16; return v.f;
}
// HW packed f32->bf16 (RNE), 1 instr per pair
__device__ __forceinline__ uint32_t cvtpk(float lo, float hi) {
    uint32_t r;
    asm("v_cvt_pk_bf16_f32 %0, %1, %2" : "=v"(r) : "v"(lo), "v"(hi));
    return r;
}
__device__ __forceinline__ uint16_t f2bf1(float f) {
    return (uint16_t)cvtpk(f, f);
}
__device__ __forceinline__ uint4 pack_bf8(float4 a, float4 b) {
    uint4 r;
    r.x = cvtpk(a.x, a.y); r.y = cvtpk(a.z, a.w);
    r.z = cvtpk(b.x, b.y); r.w = cvtpk(b.z, b.w);
    return r;
}

// raw workgroup barrier: LDS visibility only; global loads/stores stay in flight
__device__ __forceinline__ void lds_barrier() {
    asm volatile("s_waitcnt lgkmcnt(0)" ::: "memory");
    __builtin_amdgcn_s_barrier();
    __builtin_amdgcn_sched_barrier(0);
}

// Swizzled LDS layout: bf16 rows of 128 (16 chunks of 16B), XOR by row&7.
#define SWZ(row, chunk) ((row) * 128 + (((chunk) ^ ((row) & 7)) * 8))

// parent h write into swizzled bf16 LDS row
__device__ __forceinline__ void hwr(uint16_t* buf, int row, int colf, float v) {
    buf[row * 128 + (((colf >> 3) ^ (row & 7)) * 8) + (colf & 7)] = f2bf1(v);
}

__device__ __forceinline__ void wx_unpack(ushort4 g, float o[4]) {
    o[0] = bf2f(g.x); o[1] = bf2f(g.y); o[2] = bf2f(g.z); o[3] = bf2f(g.w);
}

// full gate epilogue for one 16-child tile
__device__ __forceinline__ void gate_epi(const f32x4 acc[4], const float wxj[2][4],
                                         const float cch[4], float hv[2], float cn[2]) {
    float fc[4];
#pragma unroll
    for (int r = 0; r < 4; ++r)
        fc[r] = sigmoidf_(acc[3][r] + wxj[r >> 1][3]) * cch[r];
#pragma unroll
    for (int j = 0; j < 2; ++j) {
        float ip = acc[0][2 * j] + acc[0][2 * j + 1] + wxj[j][0];
        float op = acc[1][2 * j] + acc[1][2 * j + 1] + wxj[j][1];
        float up = acc[2][2 * j] + acc[2][2 * j + 1] + wxj[j][2];
        cn[j] = sigmoidf_(ip) * tanhf_(up) + fc[2 * j] + fc[2 * j + 1];
        hv[j] = sigmoidf_(op) * tanhf_(cn[j]);
    }
}

// ---------------------------------------------------------------------------
__global__ __launch_bounds__(128) void prep_k(const float* __restrict__ Wiou,
                                              const float* __restrict__ Wf,
                                              const float* __restrict__ Uiou,
                                              const float* __restrict__ Uf,
                                              const float* __restrict__ biou,
                                              const float* __restrict__ bf,
                                              uint16_t* __restrict__ WT,
                                              uint16_t* __restrict__ UT,
                                              float* __restrict__ biasS) {
    int n = blockIdx.x, k = threadIdx.x;
    if (n < 512) {
        WT[n * 128 + k] = f2bf1(n < 384 ? Wiou[k * 384 + n] : Wf[k * 128 + (n - 384)]);
    } else if (n < 1024) {
        int m = n - 512;
        UT[m * 128 + k] = f2bf1(m < 384 ? Uiou[k * 384 + m] : Uf[k * 128 + (m - 384)]);
    } else {
#pragma unroll
        for (int r = 0; r < 4; ++r) {
            int j = r * 128 + k;
            biasS[j] = j < 384 ? biou[j] : bf[j - 384];
        }
    }
}

// ---------------------------------------------------------------------------
// GEMM for INTERNAL nodes only: wx[v*512 + col*4 + gate] (bias included).
// Grid 512: tree = bid>>4, 64 internal nodes j0..j0+63 (j < 1023).
__global__ __launch_bounds__(512, 2) void gemm_int_k(const float* __restrict__ F,
                                                     const uint16_t* __restrict__ WT,
                                                     const float* __restrict__ biasS,
                                                     uint16_t* __restrict__ wx) {
    __shared__ uint16_t Fs[64 * 128];
    const int tid = threadIdx.x;
    const int w = tid >> 6, lane = tid & 63, q = lane >> 4, l15 = lane & 15;
    const int tree = blockIdx.x >> 4;
    const int j0 = (blockIdx.x & 15) * 64;
    const int vb = tree * MTREE;
    const int srow = tid >> 4, scx = tid & 15;

    // cold F loads first
    int ja = j0 + srow;      ja = ja > 1022 ? 1022 : ja;
    int jb = j0 + 32 + srow; jb = jb > 1022 ? 1022 : jb;
    const float* sa = F + (size_t)(vb + ja) * 128 + scx * 8;
    const float* sb = F + (size_t)(vb + jb) * 128 + scx * 8;
    float4 a0 = *(const float4*)sa, a1 = *(const float4*)(sa + 4);
    float4 b0 = *(const float4*)sb, b1 = *(const float4*)(sb + 4);

    // L2-warm weights/bias after
    bf16x8 aW[4][4];
    float4 bias4[4];
#pragma unroll
    for (int s = 0; s < 4; ++s) {
        int row = (w + s * 8) * 16 + l15;
#pragma unroll
        for (int kc = 0; kc < 4; ++kc)
            aW[s][kc] = *(const bf16x8*)(WT + (size_t)row * 128 + kc * 32 + q * 8);
        bias4[s] = *(const float4*)(biasS + (w + s * 8) * 16 + q * 4);
    }

    *(uint4*)&Fs[SWZ(srow, scx)]      = pack_bf8(a0, a1);
    *(uint4*)&Fs[SWZ(32 + srow, scx)] = pack_bf8(b0, b1);
    lds_barrier();

#pragma unroll
    for (int nt = 0; nt < 4; ++nt) {
        bf16x8 b[4];
#pragma unroll
        for (int kc = 0; kc < 4; ++kc)
            b[kc] = *(const bf16x8*)&Fs[SWZ(nt * 16 + l15, kc * 4 + q)];
        f32x4 acc[4] = {};
#pragma unroll
        for (int s = 0; s < 4; ++s)
#pragma unroll
            for (int kc = 0; kc < 4; ++kc)
                acc[s] = __builtin_amdgcn_mfma_f32_16x16x32_bf16(aW[s][kc], b[kc], acc[s], 0, 0, 0);

        int j = j0 + nt * 16 + l15;
        float pi[4], po[4], pu[4], pf[4];
#pragma unroll
        for (int r = 0; r < 4; ++r) {
            pi[r] = acc[0][r] + bias4[0][r];
            po[r] = acc[1][r] + bias4[1][r];
            pu[r] = acc[2][r] + bias4[2][r];
            pf[r] = acc[3][r] + bias4[3][r];
        }
        int colb = w * 16 + q * 4;
        if (j < 1023) {
            uint4 w0, w1;
            w0.x = cvtpk(pi[0], po[0]);
            w0.y = cvtpk(pu[0], pf[0]);
            w0.z = cvtpk(pi[1], po[1]);
            w0.w = cvtpk(pu[1], pf[1]);
            w1.x = cvtpk(pi[2], po[2]);
            w1.y = cvtpk(pu[2], pf[2]);
            w1.z = cvtpk(pi[3], po[3]);
            w1.w = cvtpk(pu[3], pf[3]);
            uint16_t* wr = wx + (size_t)(vb + j) * 512 + colb * 4;
            *(uint4*)(wr) = w0;
            *(uint4*)(wr + 8) = w1;
        }
    }
}

// ---------------------------------------------------------------------------
__device__ __forceinline__ void load_bU(const uint16_t* __restrict__ UT, bf16x8 bU[4][4]) {
    const int tid = threadIdx.x;
    const int w = tid >> 6, lane = tid & 63, q = lane >> 4, l15 = lane & 15;
#pragma unroll
    for (int s = 0; s < 4; ++s) {
        int row = (w + s * 8) * 16 + l15;
#pragma unroll
        for (int kc = 0; kc < 4; ++kc)
            bU[s][kc] = *(const bf16x8*)(UT + (size_t)row * 128 + kc * 32 + q * 8);
    }
}

template<int NCT>
__device__ __forceinline__ void matvec_lds(const uint16_t* __restrict__ H,
                                           const bf16x8 bU[4][4],
                                           f32x4 acc[NCT][4], int l15, int q) {
#pragma unroll
    for (int ct = 0; ct < NCT; ++ct) {
        bf16x8 a[4];
#pragma unroll
        for (int kc = 0; kc < 4; ++kc)
            a[kc] = *(const bf16x8*)&H[SWZ(ct * 16 + l15, kc * 4 + q)];
#pragma unroll
        for (int s = 0; s < 4; ++s)
#pragma unroll
            for (int kc = 0; kc < 4; ++kc)
                acc[ct][s] = __builtin_amdgcn_mfma_f32_16x16x32_bf16(a[kc], bU[s][kc], acc[ct][s], 0, 0, 0);
    }
}

// ---------------------------------------------------------------------------
// Fused LEAF GEMM + depth-9..5 climb. Each block: 2 d5 subtrees = 64 leaves.
// Leaf h -> global out + HA LDS; leaf c -> CA LDS only (never global).
__global__ __launch_bounds__(512, 1) void fused5L_k(const float* __restrict__ F,
                                                    const uint16_t* __restrict__ WT,
                                                    const float* __restrict__ biasS,
                                                    const uint16_t* __restrict__ wx,
                                                    const uint16_t* __restrict__ UT,
                                                    float* __restrict__ h,
                                                    float* __restrict__ c) {
    __shared__ uint16_t FLS[64 * 128];  // 16 KB leaf features (bf16 swz)
    __shared__ uint16_t HA[64 * 128];   // 16 KB leaf h
    __shared__ float    CA[64 * 132];   // 33.8 KB leaf c
    __shared__ uint16_t H9[32 * 128];   // 8 KB
    __shared__ float    C9[32 * 132];   // 16.9 KB
    __shared__ uint16_t H8[16 * 128];   // 4 KB
    __shared__ float    C8[16 * 132];   // 8.45 KB
    __shared__ uint16_t H7[16 * 128];   // 4 KB (8 rows valid)
    __shared__ float    C7[16 * 132];   // 8.45 KB
    __shared__ uint16_t H6[16 * 128];   // 4 KB (4 rows valid)
    __shared__ float    C6[16 * 132];   // 8.45 KB
    const int tid = threadIdx.x;
    const int w = tid >> 6, lane = tid & 63, q = lane >> 4, l15 = lane & 15;
    const int colf = w * 16 + l15;
    const int tree = blockIdx.x >> 4;
    const int pos5 = (blockIdx.x & 15) * 2;
    const int vbase = tree * MTREE;
    const int v5 = vbase + 31 + pos5;
    const int v6 = vbase + 63 + 2 * pos5;
    const int v7 = vbase + 127 + 4 * pos5;
    const int v8 = vbase + 255 + 8 * pos5;
    const int v9 = vbase + 511 + 16 * pos5;
    const int vL = vbase + 1023 + 32 * pos5;

    // (1) staging loads FIRST: 64 leaf feature rows
    const int srow = tid >> 4, scx = tid & 15;
    const float* sa = F + (size_t)(vL + srow) * 128 + scx * 8;
    const float* sb = F + (size_t)(vL + 32 + srow) * 128 + scx * 8;
    float4 a0 = *(const float4*)sa, a1 = *(const float4*)(sa + 4);
    float4 b0 = *(const float4*)sb, b1 = *(const float4*)(sb + 4);

    // (2) W weights + bias (L2-warm)
    bf16x8 aW[4][4];
    float4 bias4[4];
#pragma unroll
    for (int s = 0; s < 4; ++s) {
        int row = (w + s * 8) * 16 + l15;
#pragma unroll
        for (int kc = 0; kc < 4; ++kc)
            aW[s][kc] = *(const bf16x8*)(WT + (size_t)row * 128 + kc * 32 + q * 8);
        bias4[s] = *(const float4*)(biasS + (w + s * 8) * 16 + q * 4);
    }

    // (3) scattered wx prefetch for d9/d8
    float wxA[4][2][4], wxB[2][2][4];
#pragma unroll
    for (int ct = 0; ct < 4; ++ct)
#pragma unroll
        for (int j = 0; j < 2; ++j) {
            int pl = ct * 8 + q * 2 + j;
            wx_unpack(*(const ushort4*)(wx + (size_t)(v9 + pl) * 512 + colf * 4), wxA[ct][j]);
        }
#pragma unroll
    for (int ct = 0; ct < 2; ++ct)
#pragma unroll
        for (int j = 0; j < 2; ++j) {
            int pl = ct * 8 + q * 2 + j;
            wx_unpack(*(const ushort4*)(wx + (size_t)(v8 + pl) * 512 + colf * 4), wxB[ct][j]);
        }

    // (4) pack F -> LDS
    *(uint4*)&FLS[SWZ(srow, scx)]      = pack_bf8(a0, a1);
    *(uint4*)&FLS[SWZ(32 + srow, scx)] = pack_bf8(b0, b1);
    lds_barrier();

    // ---- Phase 1: leaf GEMM + leaf epilogue (all 64 nodes are leaves) ----
#pragma unroll
    for (int nt = 0; nt < 4; ++nt) {
        bf16x8 b[4];
#pragma unroll
        for (int kc = 0; kc < 4; ++kc)
            b[kc] = *(const bf16x8*)&FLS[SWZ(nt * 16 + l15, kc * 4 + q)];
        f32x4 acc[4] = {};
#pragma unroll
        for (int s = 0; s < 4; ++s)
#pragma unroll
            for (int kc = 0; kc < 4; ++kc)
                acc[s] = __builtin_amdgcn_mfma_f32_16x16x32_bf16(aW[s][kc], b[kc], acc[s], 0, 0, 0);

        int row = nt * 16 + l15;
        int colb = w * 16 + q * 4;
        float cv[4], hv[4];
#pragma unroll
        for (int r = 0; r < 4; ++r) {
            float pi = acc[0][r] + bias4[0][r];
            float po = acc[1][r] + bias4[1][r];
            float pu = acc[2][r] + bias4[2][r];
            float cn = sigmoidf_(pi) * tanhf_(pu);
            cv[r] = cn;
            hv[r] = sigmoidf_(po) * tanhf_(cn);
        }
        // global h (required output)
        *(float4*)&h[(size_t)(vL + row) * 128 + colb] = *(float4*)hv;
        // HA bf16 swizzled (8B = 4 cols)
        int chunk = colb >> 3, within = colb & 7;
        uint2 hp;
        hp.x = cvtpk(hv[0], hv[1]);
        hp.y = cvtpk(hv[2], hv[3]);
        *(uint2*)&HA[row * 128 + ((chunk ^ (row & 7)) * 8) + within] = hp;
        // CA f32
        *(float4*)&CA[row * 132 + colb] = *(float4*)cv;
    }
    bf16x8 bU[4][4];
    load_bU(UT, bU);    // after aW's last use; latency hides under barrier
    lds_barrier();

    // ---- LEVEL A (d9): 32 parents from 64 leaf children (HA/CA in LDS) ----
    float wxC[2][4], wxD[2][4], wxE[2][4];
    {
        f32x4 acc[4][4] = {};
        matvec_lds<4>(HA, bU, acc, l15, q);
        // prefetch deeper-level wx while A's epilogue runs
#pragma unroll
        for (int j = 0; j < 2; ++j) {
            int pl = q * 2 + j;
            wx_unpack(*(const ushort4*)(wx + (size_t)(v7 + pl) * 512 + colf * 4), wxC[j]);
            wx_unpack(*(const ushort4*)(wx + (size_t)(v6 + pl) * 512 + colf * 4), wxD[j]);
            wx_unpack(*(const ushort4*)(wx + (size_t)(v5 + pl) * 512 + colf * 4), wxE[j]);
        }
#pragma unroll
        for (int ct = 0; ct < 4; ++ct) {
            float cch[4];
#pragma unroll
            for (int r = 0; r < 4; ++r)
                cch[r] = CA[(ct * 16 + q * 4 + r) * 132 + colf];
            float hv[2], cn[2];
            gate_epi(acc[ct], wxA[ct], cch, hv, cn);
#pragma unroll
            for (int j = 0; j < 2; ++j) {
                int pl = ct * 8 + q * 2 + j;
                h[(size_t)(v9 + pl) * 128 + colf] = hv[j];
                hwr(H9, pl, colf, hv[j]);
                C9[pl * 132 + colf] = cn[j];
            }
        }
    }
    lds_barrier();

    // ---- LEVEL B (d8): 16 parents ----
    {
        float cch[2][4];
#pragma unroll
        for (int ct = 0; ct < 2; ++ct)
#pragma unroll
            for (int r = 0; r < 4; ++r)
                cch[ct][r] = C9[(ct * 16 + q * 4 + r) * 132 + colf];
        f32x4 acc[2][4] = {};
        matvec_lds<2>(H9, bU, acc, l15, q);
#pragma unroll
        for (int ct = 0; ct < 2; ++ct) {
            float hv[2], cn[2];
            gate_epi(acc[ct], wxB[ct], cch[ct], hv, cn);
#pragma unroll
            for (int j = 0; j < 2; ++j) {
                int pl = ct * 8 + q * 2 + j;
                h[(size_t)(v8 + pl) * 128 + colf] = hv[j];
                hwr(H8, pl, colf, hv[j]);
                C8[pl * 132 + colf] = cn[j];
            }
        }
    }
    lds_barrier();

    // ---- LEVEL C (d7): 8 parents ----
    {
        float cch[4];
#pragma unroll
        for (int r = 0; r < 4; ++r)
            cch[r] = C8[(q * 4 + r) * 132 + colf];
        f32x4 acc[1][4] = {};
        matvec_lds<1>(H8, bU, acc, l15, q);
        float hv[2], cn[2];
        gate_epi(acc[0], wxC, cch, hv, cn);
#pragma unroll
        for (int j = 0; j < 2; ++j) {
            int pl = q * 2 + j;
            h[(size_t)(v7 + pl) * 128 + colf] = hv[j];
            hwr(H7, pl, colf, hv[j]);
            C7[pl * 132 + colf] = cn[j];
        }
    }
    lds_barrier();

    // ---- LEVEL D (d6): 4 parents ----
    {
        float cch[4];
#pragma unroll
        for (int r = 0; r < 4; ++r)
            cch[r] = C7[(q * 4 + r) * 132 + colf];
        f32x4 acc[1][4] = {};
        matvec_lds<1>(H7, bU, acc, l15, q);
        float hv[2], cn[2];
        gate_epi(acc[0], wxD, cch, hv, cn);
#pragma unroll
        for (int j = 0; j < 2; ++j) {
            int pl = q * 2 + j;
            if (pl < 4) {
                h[(size_t)(v6 + pl) * 128 + colf] = hv[j];
                hwr(H6, pl, colf, hv[j]);
                C6[pl * 132 + colf] = cn[j];
            }
        }
    }
    lds_barrier();

    // ---- LEVEL E (d5): 2 parents -> global h + c ----
    {
        float cch[4];
#pragma unroll
        for (int r = 0; r < 4; ++r)
            cch[r] = C6[(q * 4 + r) * 132 + colf];
        f32x4 acc[1][4] = {};
        matvec_lds<1>(H6, bU, acc, l15, q);
        float hv[2], cn[2];
        gate_epi(acc[0], wxE, cch, hv, cn);
#pragma unroll
        for (int j = 0; j < 2; ++j) {
            int pl = q * 2 + j;
            if (pl < 2) {
                h[(size_t)(v5 + pl) * 128 + colf] = hv[j];
                c[(size_t)(v5 + pl) * 128 + colf] = cn[j];
            }
        }
    }
}

// ---------------------------------------------------------------------------
// Tail: dep 4..0 (5 small groups), one block per tree. Unchanged from R11.
__global__ __launch_bounds__(512, 1) void tail_k(const uint16_t* __restrict__ wx,
                                                 const uint16_t* __restrict__ UT,
                                                 const float* __restrict__ cglob,
                                                 float* __restrict__ h) {
    __shared__ uint16_t Hbuf[48 * 128];   // 12 KB
    __shared__ float CS[32 * 132];        // 16.9 KB
    bf16x8 bU[4][4];
    load_bU(UT, bU);
    const int tree = blockIdx.x;
    const int tid = threadIdx.x;
    const int w = tid >> 6, lane = tid & 63, q = lane >> 4, l15 = lane & 15;
    const int colf = w * 16 + l15;
    const int vbase = tree * MTREE;

    // (1) staging loads first: d5 h = nodes vbase+31..62
    const int srow = tid >> 4, scx = tid & 15;
    const float* ssrc = h + (size_t)(vbase + 31 + srow) * 128 + scx * 8;
    float4 s0 = *(const float4*)ssrc;
    float4 s1 = *(const float4*)(ssrc + 4);

    // (2) scattered prefetch: all 5 groups' wx + d5 c
    float wx0[2][2][4], wx1[2][4], wx2[2][4], wx3[2][4], wx4[2][4];
#pragma unroll
    for (int ct = 0; ct < 2; ++ct)
#pragma unroll
        for (int j = 0; j < 2; ++j) {
            int pl = ct * 8 + q * 2 + j;
            wx_unpack(*(const ushort4*)(wx + (size_t)(vbase + 15 + pl) * 512 + colf * 4), wx0[ct][j]);
        }
#pragma unroll
    for (int j = 0; j < 2; ++j) {
        int pl = q * 2 + j;
        wx_unpack(*(const ushort4*)(wx + (size_t)(vbase + 7 + pl) * 512 + colf * 4), wx1[j]);
        wx_unpack(*(const ushort4*)(wx + (size_t)(vbase + 3 + pl) * 512 + colf * 4), wx2[j]);
        wx_unpack(*(const ushort4*)(wx + (size_t)(vbase + 1 + pl) * 512 + colf * 4), wx3[j]);
        wx_unpack(*(const ushort4*)(wx + (size_t)(vbase + 0 + pl) * 512 + colf * 4), wx4[j]);
    }
    float cgl[2][4];
#pragma unroll
    for (int ct = 0; ct < 2; ++ct)
#pragma unroll
        for (int r = 0; r < 4; ++r) {
            int cl = ct * 16 + q * 4 + r;
            cgl[ct][r] = cglob[(size_t)(vbase + 31 + cl) * 128 + colf];
        }

    // (3) pack staging -> Hbuf rows 0..31
    *(uint4*)&Hbuf[SWZ(srow, scx)] = pack_bf8(s0, s1);
    lds_barrier();

    // ---- G0: dep4, 16 parents
    {
        f32x4 acc[2][4] = {};
        matvec_lds<2>(Hbuf, bU, acc, l15, q);
#pragma unroll
        for (int ct = 0; ct < 2; ++ct) {
            float hv[2], cn[2];
            gate_epi(acc[ct], wx0[ct], cgl[ct], hv, cn);
#pragma unroll
            for (int j = 0; j < 2; ++j) {
                int pl = ct * 8 + q * 2 + j;
                h[(size_t)(vbase + 15 + pl) * 128 + colf] = hv[j];
                hwr(Hbuf, 32 + pl, colf, hv[j]);
                CS[pl * 132 + colf] = cn[j];
            }
        }
    }
    lds_barrier();

    // ---- G1: dep3, 8 parents
    {
        float cch[4];
#pragma unroll
        for (int r = 0; r < 4; ++r)
            cch[r] = CS[(q * 4 + r) * 132 + colf];
        f32x4 acc[1][4] = {};
        matvec_lds<1>(&Hbuf[32 * 128], bU, acc, l15, q);
        float hv[2], cn[2];
        gate_epi(acc[0], wx1, cch, hv, cn);
#pragma unroll
        for (int j = 0; j < 2; ++j) {
            int pl = q * 2 + j;
            h[(size_t)(vbase + 7 + pl) * 128 + colf] = hv[j];
            hwr(Hbuf, pl, colf, hv[j]);
            CS[(16 + pl) * 132 + colf] = cn[j];
        }
    }
    lds_barrier();

    // ---- G2: dep2, 4 parents
    {
        float cch[4];
#pragma unroll
        for (int r = 0; r < 4; ++r)
            cch[r] = CS[(16 + q * 4 + r) * 132 + colf];
        f32x4 acc[1][4] = {};
        matvec_lds<1>(Hbuf, bU, acc, l15, q);
        float hv[2], cn[2];
        gate_epi(acc[0], wx2, cch, hv, cn);
#pragma unroll
        for (int j = 0; j < 2; ++j) {
            int pl = q * 2 + j;
            if (pl < 4) {
                h[(size_t)(vbase + 3 + pl) * 128 + colf] = hv[j];
                hwr(Hbuf, 32 + pl, colf, hv[j]);
                CS[pl * 132 + colf] = cn[j];
            }
        }
    }
    lds_barrier();

    // ---- G3: dep1, 2 parents
    {
        float cch[4];
#pragma unroll
        for (int r = 0; r < 4; ++r)
            cch[r] = CS[(q * 4 + r) * 132 + colf];
        f32x4 acc[1][4] = {};
        matvec_lds<1>(&Hbuf[32 * 128], bU, acc, l15, q);
        float hv[2], cn[2];
        gate_epi(acc[0], wx3, cch, hv, cn);
#pragma unroll
        for (int j = 0; j < 2; ++j) {
            int pl = q * 2 + j;
            if (pl < 2) {
                h[(size_t)(vbase + 1 + pl) * 128 + colf] = hv[j];
                hwr(Hbuf, pl, colf, hv[j]);
                CS[(16 + pl) * 132 + colf] = cn[j];
            }
        }
    }
    lds_barrier();

    // ---- G4: dep0, root
    {
        float cch[4];
#pragma unroll
        for (int r = 0; r < 4; ++r)
            cch[r] = CS[(16 + q * 4 + r) * 132 + colf];
        f32x4 acc[1][4] = {};
        matvec_lds<1>(Hbuf, bU, acc, l15, q);
        float hv[2], cn[2];
        gate_epi(acc[0], wx4, cch, hv, cn);
        if (q == 0) {
            h[(size_t)vbase * 128 + colf] = hv[0];
        }
    }
}

// ---------------------------------------------------------------------------
extern "C" void kernel_launch(void* const* d_in, const int* in_sizes, int n_in,
                              void* d_out, int out_size, void* d_ws, size_t ws_size,
                              hipStream_t stream) {
    const float* features = (const float*)d_in[0];
    const float* W_iou    = (const float*)d_in[1];
    const float* b_iou    = (const float*)d_in[2];
    const float* U_iou    = (const float*)d_in[3];
    const float* W_f      = (const float*)d_in[4];
    const float* b_f      = (const float*)d_in[5];
    const float* U_f      = (const float*)d_in[6];
    float* h = (float*)d_out;

    char* wp = (char*)d_ws;
    uint16_t* wx    = (uint16_t*)wp; wp += (size_t)NNODES * 512 * 2;
    float*    c     = (float*)wp;    wp += (size_t)NNODES * 128 * 4;
    uint16_t* WT    = (uint16_t*)wp; wp += 512 * 128 * 2;
    uint16_t* UT    = (uint16_t*)wp; wp += 512 * 128 * 2;
    float*    biasS = (float*)wp;    wp += 512 * 4;

    hipLaunchKernelGGL(prep_k, dim3(1025), dim3(128), 0, stream,
                       W_iou, W_f, U_iou, U_f, b_iou, b_f, WT, UT, biasS);
    hipLaunchKernelGGL(gemm_int_k, dim3(512), dim3(512), 0, stream,
                       features, WT, biasS, wx);
    hipLaunchKernelGGL(fused5L_k, dim3(512), dim3(512), 0, stream,
                       features, WT, biasS, wx, UT, h, c);
    hipLaunchKernelGGL(tail_k, dim3(32), dim3(512), 0, stream, wx, UT, c, h);
}